// Round 11
// baseline (443.301 us; speedup 1.0000x reference)
//
#include <hip/hip_runtime.h>
#include <math.h>
#include <stdint.h>

#define DIM_ 1024
#define HEADS_ 16
#define DK_ 64
#define B_ 2
#define L_ 2048
#define BH_ (B_*HEADS_)
#define M_ (B_*L_)

typedef __attribute__((ext_vector_type(4))) float f32x4;
typedef __attribute__((ext_vector_type(8))) short bf16x8;
typedef __attribute__((ext_vector_type(4))) short bf16x4;

#define QSCALE 0.18033688f   // 0.125 * log2(e): softmax in exp2 domain

static __device__ __forceinline__ short f2bf(float f) {
    uint32_t u = __builtin_bit_cast(uint32_t, f);
    u += 0x7fffu + ((u >> 16) & 1u);
    return (short)(u >> 16);
}
static __device__ __forceinline__ void gload16(const void* g, void* l) {
    __builtin_amdgcn_global_load_lds(
        (const __attribute__((address_space(1))) unsigned int*)g,
        (__attribute__((address_space(3))) unsigned int*)l, 16, 0, 0);
}

// ------------------------------------------------------------ prep (fused): fp32->bf16 cvt + W transpose
__global__ __launch_bounds__(256)
void prep(const float* __restrict__ xout, const float* __restrict__ xctx,
          const float* __restrict__ Wq, const float* __restrict__ Wk,
          const float* __restrict__ Wv, const float* __restrict__ Wo,
          short* __restrict__ xoutb, short* __restrict__ xctxb,
          short* __restrict__ WqT, short* __restrict__ WkT,
          short* __restrict__ WvT, short* __restrict__ WoT)
{
    __shared__ float ts[64][65];
    const int bid = blockIdx.x;
    const int tid = threadIdx.x;
    if (bid < 4096) {
        const int id = bid * 256 + tid;
        const int nA = (M_ * DIM_) / 8;
        const float* src = (id < nA) ? xout : xctx;
        short* dst = (id < nA) ? xoutb : xctxb;
        const int c = (id < nA) ? id : id - nA;
        const f32x4 v0 = *(const f32x4*)&src[(size_t)c * 8];
        const f32x4 v1 = *(const f32x4*)&src[(size_t)c * 8 + 4];
        bf16x8 o;
#pragma unroll
        for (int i = 0; i < 4; ++i) { o[i] = f2bf(v0[i]); o[4 + i] = f2bf(v1[i]); }
        *(bf16x8*)&dst[(size_t)c * 8] = o;
        return;
    }
    const int flat = bid - 4096;
    const int z = flat >> 9;
    const int rem = flat & 511;
    const int K = (z == 3) ? 2 * DIM_ : DIM_;
    const int k0 = (rem & 31) * 64;
    if (k0 >= K) return;
    const int n0 = (rem >> 5) * 64;
    const float* W = (z == 0) ? Wq : (z == 1) ? Wk : (z == 2) ? Wv : Wo;
    short* WT = (z == 0) ? WqT : (z == 1) ? WkT : (z == 2) ? WvT : WoT;
    {
        const int k = tid >> 2, noff = (tid & 3) * 16;
#pragma unroll
        for (int i = 0; i < 4; ++i)
            *(f32x4*)&ts[k][noff + i * 4] =
                *(const f32x4*)&W[(size_t)(k0 + k) * DIM_ + n0 + noff + i * 4];
    }
    __syncthreads();
    {
        const int n = tid >> 2, koff = (tid & 3) * 16;
#pragma unroll
        for (int c = 0; c < 2; ++c) {
            bf16x8 o;
#pragma unroll
            for (int i = 0; i < 8; ++i) o[i] = f2bf(ts[koff + c * 8 + i][n]);
            *(bf16x8*)&WT[(size_t)(n0 + n) * K + k0 + koff + c * 8] = o;
        }
    }
}

// ------------------------------------------------------------ QKV GEMM (MFMA, gload_lds, BK=64, XOR-swizzled LDS)
__global__ __launch_bounds__(256)
void qkv_mfma(const short* __restrict__ xoutb, const short* __restrict__ xctxb,
              const short* __restrict__ WqT, const short* __restrict__ WkT,
              const short* __restrict__ WvT,
              const float* __restrict__ bq, const float* __restrict__ bk,
              const float* __restrict__ bv,
              short* __restrict__ qh, short* __restrict__ kh, short* __restrict__ vT)
{
    const int z = blockIdx.z;
    const short* A  = (z == 0) ? xoutb : xctxb;
    const short* Bt = (z == 0) ? WqT : (z == 1) ? WkT : WvT;
    const float* bias = (z == 0) ? bq : (z == 1) ? bk : bv;

    const int flat = blockIdx.y * 8 + blockIdx.x;
    const int wgs = (flat & 7) * 32 + (flat >> 3);
    const int col0 = (wgs & 7) * 128;
    const int row0 = (wgs >> 3) * 128;
    const int tid = threadIdx.x;
    const int lane = tid & 63;
    const int w = tid >> 6;
    const int wm = (w >> 1) * 64, wn = (w & 1) * 64;
    const int l15 = lane & 15, g = lane >> 4;
    const int sub = lane >> 3, slt = lane & 7;

    __shared__ short As[128 * 64];
    __shared__ short Bs[128 * 64];

    const short* pA[4]; const short* pB[4]; short* ldsA[4]; short* ldsB[4];
#pragma unroll
    for (int i = 0; i < 4; ++i) {
        const int r = w * 32 + i * 8 + sub;
        const int sc = ((slt ^ (r & 7)) * 8);
        pA[i] = A  + (size_t)(row0 + r) * DIM_ + sc;
        pB[i] = Bt + (size_t)(col0 + r) * DIM_ + sc;
        ldsA[i] = &As[(w * 32 + i * 8) * 64];
        ldsB[i] = &Bs[(w * 32 + i * 8) * 64];
    }

    f32x4 acc[4][4];
#pragma unroll
    for (int mi = 0; mi < 4; ++mi)
#pragma unroll
        for (int ni = 0; ni < 4; ++ni) acc[mi][ni] = (f32x4)0.f;

    for (int k0 = 0; k0 < DIM_; k0 += 64) {
#pragma unroll
        for (int i = 0; i < 4; ++i) {
            gload16(pA[i] + k0, ldsA[i]);
            gload16(pB[i] + k0, ldsB[i]);
        }
        __syncthreads();
        bf16x8 af[4][2], bfr[4][2];
#pragma unroll
        for (int mi = 0; mi < 4; ++mi) {
            const int wa = wm + mi * 16 + l15;
#pragma unroll
            for (int ks = 0; ks < 2; ++ks)
                af[mi][ks] = *(const bf16x8*)&As[wa * 64 + (((ks * 4 + g) ^ (wa & 7)) * 8)];
        }
#pragma unroll
        for (int ni = 0; ni < 4; ++ni) {
            const int wb = wn + ni * 16 + l15;
#pragma unroll
            for (int ks = 0; ks < 2; ++ks)
                bfr[ni][ks] = *(const bf16x8*)&Bs[wb * 64 + (((ks * 4 + g) ^ (wb & 7)) * 8)];
        }
        __builtin_amdgcn_s_setprio(1);
#pragma unroll
        for (int mi = 0; mi < 4; ++mi)
#pragma unroll
            for (int ni = 0; ni < 4; ++ni)
#pragma unroll
                for (int ks = 0; ks < 2; ++ks)
                    acc[mi][ni] = __builtin_amdgcn_mfma_f32_16x16x32_bf16(af[mi][ks], bfr[ni][ks], acc[mi][ni], 0, 0, 0);
        __builtin_amdgcn_s_setprio(0);
        __syncthreads();
    }

#pragma unroll
    for (int ni = 0; ni < 4; ++ni) {
        const int col = col0 + wn + ni * 16 + l15;
        const int h = col >> 6, dk = col & 63;
        const float bb = bias[col];
#pragma unroll
        for (int mi = 0; mi < 4; ++mi) {
            const int rowb = row0 + wm + mi * 16 + g * 4;
            const int b = rowb >> 11;
            const int l = rowb & (L_ - 1);
            const int bh = b * 16 + h;
            if (z == 2) {
                bf16x4 o;
#pragma unroll
                for (int r = 0; r < 4; ++r) o[r] = f2bf(acc[mi][ni][r] + bb);
                *(bf16x4*)&vT[(size_t)(bh * 64 + dk) * L_ + l] = o;
            } else {
                short* dst = (z == 0) ? qh : kh;
                const float sc = (z == 0) ? QSCALE : 1.0f;
#pragma unroll
                for (int r = 0; r < 4; ++r)
                    dst[((size_t)bh * L_ + l + r) * DK_ + dk] = f2bf((acc[mi][ni][r] + bb) * sc);
            }
        }
    }
}

// ------------------------------------------------------------ fused attention v9
// BARRIER-FREE hot loops: K/V fragments loaded directly from global (L2-resident,
// XCD-pinned). Psb is intra-wave scratch (lgkmcnt-only ordering). Waves free-run.
__global__ __launch_bounds__(512)
void attn_mfma(const short* __restrict__ qh, const short* __restrict__ kh,
               const short* __restrict__ vT,
               float* __restrict__ attn, short* __restrict__ ctxTb)
{
    const int bid = blockIdx.x;
    const int wg = (bid & 7) * 128 + (bid >> 3);      // XCD-contiguous: 4 heads per XCD
    const int bh = wg >> 5;
    const int q0 = (wg & 31) * 64;

    const int tid = threadIdx.x;
    const int lane = tid & 63;
    const int w = tid >> 6;
    const int wq = w >> 1, wk = w & 1;
    const int l15 = lane & 15, g = lane >> 4;

    // arena: scr=[0..4k), scr1=[4k..8k), Psb=[12288..16896), stat after
    __shared__ short SM[17408];
    short* const Psb = SM + 12288;                    // 64 x 72 bf16 (intra-wave)
    float* const stat = (float*)(SM + 16896);         // [4][2][16][2]

    const short* kbase = kh + (size_t)bh * (L_ * DK_);
    const short* vbase = vT + (size_t)bh * (DK_ * L_);

    bf16x8 qf[2];
#pragma unroll
    for (int ks = 0; ks < 2; ++ks)
        qf[ks] = *(const bf16x8*)&qh[((size_t)bh * L_ + q0 + wq * 16 + l15) * DK_ + ks * 32 + g * 8];

    // per-lane fragment offsets (elements)
    int kfOff[2][2], vfOff[4];
#pragma unroll
    for (int cc = 0; cc < 2; ++cc)
#pragma unroll
        for (int ks = 0; ks < 2; ++ks)
            kfOff[cc][ks] = (wk * 32 + cc * 16 + l15) * 64 + ks * 32 + g * 8;
#pragma unroll
    for (int nf = 0; nf < 4; ++nf)
        vfOff[nf] = (nf * 16 + l15) * L_ + wk * 32 + g * 8;

    // ---------------- pass 1: online stats — zero barriers, reg ping-pong
    float m[4], s[4];
#pragma unroll
    for (int r = 0; r < 4; ++r) { m[r] = -1e30f; s[r] = 0.f; }

    bf16x8 kA[2][2], kB[2][2];
#pragma unroll
    for (int cc = 0; cc < 2; ++cc)
#pragma unroll
        for (int ks = 0; ks < 2; ++ks)
            kA[cc][ks] = *(const bf16x8*)&kbase[kfOff[cc][ks]];

    for (int t = 0; t < 32; t += 2) {
        // prefetch t+1 into kB
        if (t + 1 < 32) {
            const short* kt = kbase + (size_t)(t + 1) * 64 * DK_;
#pragma unroll
            for (int cc = 0; cc < 2; ++cc)
#pragma unroll
                for (int ks = 0; ks < 2; ++ks)
                    kB[cc][ks] = *(const bf16x8*)&kt[kfOff[cc][ks]];
        }
        {
            f32x4 sa0 = (f32x4)0.f, sa1 = (f32x4)0.f;
            __builtin_amdgcn_s_setprio(1);
            sa0 = __builtin_amdgcn_mfma_f32_16x16x32_bf16(qf[0], kA[0][0], sa0, 0, 0, 0);
            sa0 = __builtin_amdgcn_mfma_f32_16x16x32_bf16(qf[1], kA[0][1], sa0, 0, 0, 0);
            sa1 = __builtin_amdgcn_mfma_f32_16x16x32_bf16(qf[0], kA[1][0], sa1, 0, 0, 0);
            sa1 = __builtin_amdgcn_mfma_f32_16x16x32_bf16(qf[1], kA[1][1], sa1, 0, 0, 0);
            __builtin_amdgcn_s_setprio(0);
#pragma unroll
            for (int r = 0; r < 4; ++r) {
                const float tm = fmaxf(sa0[r], sa1[r]);
                const float mn = fmaxf(m[r], tm);
                s[r] = s[r] * exp2f(m[r] - mn) + exp2f(sa0[r] - mn) + exp2f(sa1[r] - mn);
                m[r] = mn;
            }
        }
        // prefetch t+2 into kA
        if (t + 2 < 32) {
            const short* kt = kbase + (size_t)(t + 2) * 64 * DK_;
#pragma unroll
            for (int cc = 0; cc < 2; ++cc)
#pragma unroll
                for (int ks = 0; ks < 2; ++ks)
                    kA[cc][ks] = *(const bf16x8*)&kt[kfOff[cc][ks]];
        }
        {
            f32x4 sa0 = (f32x4)0.f, sa1 = (f32x4)0.f;
            __builtin_amdgcn_s_setprio(1);
            sa0 = __builtin_amdgcn_mfma_f32_16x16x32_bf16(qf[0], kB[0][0], sa0, 0, 0, 0);
            sa0 = __builtin_amdgcn_mfma_f32_16x16x32_bf16(qf[1], kB[0][1], sa0, 0, 0, 0);
            sa1 = __builtin_amdgcn_mfma_f32_16x16x32_bf16(qf[0], kB[1][0], sa1, 0, 0, 0);
            sa1 = __builtin_amdgcn_mfma_f32_16x16x32_bf16(qf[1], kB[1][1], sa1, 0, 0, 0);
            __builtin_amdgcn_s_setprio(0);
#pragma unroll
            for (int r = 0; r < 4; ++r) {
                const float tm = fmaxf(sa0[r], sa1[r]);
                const float mn = fmaxf(m[r], tm);
                s[r] = s[r] * exp2f(m[r] - mn) + exp2f(sa0[r] - mn) + exp2f(sa1[r] - mn);
                m[r] = mn;
            }
        }
    }
#pragma unroll
    for (int mask = 1; mask <= 8; mask <<= 1) {
#pragma unroll
        for (int r = 0; r < 4; ++r) {
            const float mo = __shfl_xor(m[r], mask);
            const float so = __shfl_xor(s[r], mask);
            const float mn = fmaxf(m[r], mo);
            s[r] = s[r] * exp2f(m[r] - mn) + so * exp2f(mo - mn);
            m[r] = mn;
        }
    }
    if (l15 == 0) {
#pragma unroll
        for (int r = 0; r < 4; ++r) {
            stat[((wq * 2 + wk) * 16 + g * 4 + r) * 2 + 0] = m[r];
            stat[((wq * 2 + wk) * 16 + g * 4 + r) * 2 + 1] = s[r];
        }
    }
    __syncthreads();
    float inv_s[4];
#pragma unroll
    for (int r = 0; r < 4; ++r) {
        const float m0 = stat[((wq * 2 + 0) * 16 + g * 4 + r) * 2 + 0];
        const float s0 = stat[((wq * 2 + 0) * 16 + g * 4 + r) * 2 + 1];
        const float m1 = stat[((wq * 2 + 1) * 16 + g * 4 + r) * 2 + 0];
        const float s1 = stat[((wq * 2 + 1) * 16 + g * 4 + r) * 2 + 1];
        const float mn = fmaxf(m0, m1);
        m[r] = mn;
        inv_s[r] = 1.0f / (s0 * exp2f(m0 - mn) + s1 * exp2f(m1 - mn));
    }

    f32x4 cacc[4];
#pragma unroll
    for (int nf = 0; nf < 4; ++nf) cacc[nf] = (f32x4)0.f;

    float* attnB = attn + ((size_t)bh * L_ + q0) * L_;
    short* const psW = &Psb[(wq * 16 + g * 4) * 72 + wk * 32 + l15];   // write base (col part)
    const short* const psR = &Psb[(wq * 16 + l15) * 72 + wk * 32 + g * 8];

    // ---------------- pass 2: barrier-free; Psb intra-wave; stores free-fly
    for (int t = 0; t < 32; ++t) {
        const short* kt = kbase + (size_t)t * 64 * DK_;
        const short* vt = vbase + t * 64;
        bf16x8 kf00, kf01, kf10, kf11, vf0, vf1, vf2, vf3;
        kf00 = *(const bf16x8*)&kt[kfOff[0][0]];
        kf01 = *(const bf16x8*)&kt[kfOff[0][1]];
        kf10 = *(const bf16x8*)&kt[kfOff[1][0]];
        kf11 = *(const bf16x8*)&kt[kfOff[1][1]];
        vf0 = *(const bf16x8*)&vt[vfOff[0]];
        vf1 = *(const bf16x8*)&vt[vfOff[1]];
        vf2 = *(const bf16x8*)&vt[vfOff[2]];
        vf3 = *(const bf16x8*)&vt[vfOff[3]];

        f32x4 sa0 = (f32x4)0.f, sa1 = (f32x4)0.f;
        __builtin_amdgcn_s_setprio(1);
        sa0 = __builtin_amdgcn_mfma_f32_16x16x32_bf16(qf[0], kf00, sa0, 0, 0, 0);
        sa0 = __builtin_amdgcn_mfma_f32_16x16x32_bf16(qf[1], kf01, sa0, 0, 0, 0);
        sa1 = __builtin_amdgcn_mfma_f32_16x16x32_bf16(qf[0], kf10, sa1, 0, 0, 0);
        sa1 = __builtin_amdgcn_mfma_f32_16x16x32_bf16(qf[1], kf11, sa1, 0, 0, 0);
        __builtin_amdgcn_s_setprio(0);

        float* aB = attnB + (size_t)(wq * 16 + g * 4) * L_ + t * 64 + wk * 32 + l15;
#pragma unroll
        for (int r = 0; r < 4; ++r) {
            const float p0 = exp2f(sa0[r] - m[r]) * inv_s[r];
            const float p1 = exp2f(sa1[r] - m[r]) * inv_s[r];
            psW[r * 72 + 0]  = f2bf(p0);
            psW[r * 72 + 16] = f2bf(p1);
            __builtin_nontemporal_store(p0, aB + (size_t)r * L_);
            __builtin_nontemporal_store(p1, aB + (size_t)r * L_ + 16);
        }
        asm volatile("s_waitcnt lgkmcnt(0)" ::: "memory");   // own ds_writes done
        __builtin_amdgcn_sched_barrier(0);
        const bf16x8 pa = *(const bf16x8*)psR;
        __builtin_amdgcn_s_setprio(1);
        cacc[0] = __builtin_amdgcn_mfma_f32_16x16x32_bf16(pa, vf0, cacc[0], 0, 0, 0);
        cacc[1] = __builtin_amdgcn_mfma_f32_16x16x32_bf16(pa, vf1, cacc[1], 0, 0, 0);
        cacc[2] = __builtin_amdgcn_mfma_f32_16x16x32_bf16(pa, vf2, cacc[2], 0, 0, 0);
        cacc[3] = __builtin_amdgcn_mfma_f32_16x16x32_bf16(pa, vf3, cacc[3], 0, 0, 0);
        __builtin_amdgcn_s_setprio(0);
    }

    // epilogue: combine kv-halves, store ctx^T bf16
    __syncthreads();
    float* scr = (float*)SM;
    float* scr1 = (float*)(SM + 4096);
    if (wk) {
#pragma unroll
        for (int nf = 0; nf < 4; ++nf) {
            float* p = (nf < 2) ? scr : scr1;
            *(f32x4*)&p[(((wq * 2) + (nf & 1)) * 64 + lane) * 4] = cacc[nf];
        }
    }
    __syncthreads();
    if (!wk) {
#pragma unroll
        for (int nf = 0; nf < 4; ++nf) {
            const float* p = (nf < 2) ? scr : scr1;
            const f32x4 o = cacc[nf] + *(const f32x4*)&p[(((wq * 2) + (nf & 1)) * 64 + lane) * 4];
            bf16x4 ob;
#pragma unroll
            for (int r = 0; r < 4; ++r) ob[r] = f2bf(o[r]);
            *(bf16x4*)&ctxTb[(size_t)(bh * 64 + nf * 16 + l15) * L_ + q0 + wq * 16 + g * 4] = ob;
        }
    }
}

// ------------------------------------------------------------ output projection (MFMA, BM=128 BN=64, 2 blocks/CU)
__global__ __launch_bounds__(256)
void out_mfma(const short* __restrict__ ctxTb, const short* __restrict__ xoutb,
              const short* __restrict__ WoT, const float* __restrict__ bo,
              float* __restrict__ out)
{
    const int flat = blockIdx.y * 16 + blockIdx.x;
    const int wgs = (flat & 7) * 64 + (flat >> 3);
    const int col0 = (wgs & 15) * 64;
    const int row0 = (wgs >> 4) * 128;
    const int tid = threadIdx.x;
    const int lane = tid & 63;
    const int w = tid >> 6;
    const int wm = (w >> 1) * 64, wn = (w & 1) * 32;
    const int l15 = lane & 15, g = lane >> 4;
    const int sub = lane >> 3, slt = lane & 7;

    __shared__ short As[128 * 64];
    __shared__ short Bs[64 * 64];

    const short* pA1[4]; const short* pA2[4]; const short* pB[2];
    short* ldsA[4]; short* ldsB[2];
#pragma unroll
    for (int i = 0; i < 4; ++i) {
        const int r = w * 32 + i * 8 + sub;
        const int rr = row0 + r;
        const int b = rr >> 11, l_ = rr & (L_ - 1);
        const int bh = b * 16 + (l_ >> 7), d = (l_ & 127) >> 1;
        const size_t off1 = ((size_t)(bh * 64 + d) << 11) + (size_t)((l_ & 1) << 10);
        const int sc = ((slt ^ (r & 7)) * 8);
        pA1[i] = ctxTb + off1 + sc;
        pA2[i] = xoutb + (size_t)rr * DIM_ + sc;
        ldsA[i] = &As[(w * 32 + i * 8) * 64];
    }
#pragma unroll
    for (int i = 0; i < 2; ++i) {
        const int r = w * 16 + i * 8 + sub;
        const int sc = ((slt ^ (r & 7)) * 8);
        pB[i]  = WoT + (size_t)(col0 + r) * (2 * DIM_) + sc;
        ldsB[i] = &Bs[(w * 16 + i * 8) * 64];
    }

    f32x4 acc[4][2];
#pragma unroll
    for (int mi = 0; mi < 4; ++mi)
#pragma unroll
        for (int ni = 0; ni < 2; ++ni) acc[mi][ni] = (f32x4)0.f;

    for (int k0 = 0; k0 < 2 * DIM_; k0 += 64) {
        const bool first = (k0 < DIM_);
        const int kk = first ? k0 : k0 - DIM_;
#pragma unroll
        for (int i = 0; i < 4; ++i)
            gload16(first ? (pA1[i] + kk) : (pA2[i] + kk), ldsA[i]);
#pragma unroll
        for (int i = 0; i < 2; ++i)
            gload16(pB[i] + k0, ldsB[i]);
        __syncthreads();
        bf16x8 af[4][2], bfr[2][2];
#pragma unroll
        for (int mi = 0; mi < 4; ++mi) {
            const int wa = wm + mi * 16 + l15;
#pragma unroll
            for (int ks = 0; ks < 2; ++ks)
                af[mi][ks] = *(const bf16x8*)&As[wa * 64 + (((ks * 4 + g) ^ (wa & 7)) * 8)];
        }
#pragma unroll
        for (int ni = 0; ni < 2; ++ni) {
            const int wb = wn + ni * 16 + l15;
#pragma unroll
            for (int ks = 0; ks < 2; ++ks)
                bfr[ni][ks] = *(const bf16x8*)&Bs[wb * 64 + (((ks * 4 + g) ^ (wb & 7)) * 8)];
        }
        __builtin_amdgcn_s_setprio(1);
#pragma unroll
        for (int mi = 0; mi < 4; ++mi)
#pragma unroll
            for (int ni = 0; ni < 2; ++ni)
#pragma unroll
                for (int ks = 0; ks < 2; ++ks)
                    acc[mi][ni] = __builtin_amdgcn_mfma_f32_16x16x32_bf16(af[mi][ks], bfr[ni][ks], acc[mi][ni], 0, 0, 0);
        __builtin_amdgcn_s_setprio(0);
        __syncthreads();
    }

#pragma unroll
    for (int ni = 0; ni < 2; ++ni) {
        const int col = col0 + wn + ni * 16 + l15;
        const float bb = bo[col];
#pragma unroll
        for (int mi = 0; mi < 4; ++mi) {
            const int rowb = row0 + wm + mi * 16 + g * 4;
#pragma unroll
            for (int r = 0; r < 4; ++r)
                out[(size_t)(rowb + r) * DIM_ + col] = tanhf(acc[mi][ni][r] + bb);
        }
    }
}

// ------------------------------------------------------------ launch
extern "C" void kernel_launch(void* const* d_in, const int* in_sizes, int n_in,
                              void* d_out, int out_size, void* d_ws, size_t ws_size,
                              hipStream_t stream)
{
    const float* xout = (const float*)d_in[0];
    const float* xctx = (const float*)d_in[1];
    const float* Wq = (const float*)d_in[2];
    const float* bq = (const float*)d_in[3];
    const float* Wk = (const float*)d_in[4];
    const float* bk = (const float*)d_in[5];
    const float* Wv = (const float*)d_in[6];
    const float* bv = (const float*)d_in[7];
    const float* Wo = (const float*)d_in[8];
    const float* bo = (const float*)d_in[9];

    float* out  = (float*)d_out;
    float* attn = out + (size_t)M_ * DIM_;

    short* ws = (short*)d_ws;
    short* xoutb = ws;
    short* xctxb = xoutb + (size_t)M_ * DIM_;
    short* WqT   = xctxb + (size_t)M_ * DIM_;
    short* WkT   = WqT + (size_t)DIM_ * DIM_;
    short* WvT   = WkT + (size_t)DIM_ * DIM_;
    short* WoT   = WvT + (size_t)DIM_ * DIM_;
    short* qh    = WoT + (size_t)2 * DIM_ * DIM_;
    short* kh    = qh + (size_t)BH_ * L_ * DK_;
    short* vT    = kh + (size_t)BH_ * L_ * DK_;
    short* ctxTb = vT + (size_t)BH_ * L_ * DK_;

    prep<<<6144, 256, 0, stream>>>(xout, xctx, Wq, Wk, Wv, Wo,
                                   xoutb, xctxb, WqT, WkT, WvT, WoT);
    qkv_mfma<<<dim3(8, 32, 3), 256, 0, stream>>>(
        xoutb, xctxb, WqT, WkT, WvT, bq, bk, bv, qh, kh, vT);
    attn_mfma<<<1024, 512, 0, stream>>>(qh, kh, vT, attn, ctxTb);
    out_mfma<<<dim3(16, 32), 256, 0, stream>>>(ctxTb, xoutb, WoT, bo, out);
}

// Round 12
// 302.615 us; speedup vs baseline: 1.4649x; 1.4649x over previous
//
#include <hip/hip_runtime.h>
#include <math.h>
#include <stdint.h>

#define DIM_ 1024
#define HEADS_ 16
#define DK_ 64
#define B_ 2
#define L_ 2048
#define BH_ (B_*HEADS_)
#define M_ (B_*L_)

typedef __attribute__((ext_vector_type(4))) float f32x4;
typedef __attribute__((ext_vector_type(8))) short bf16x8;
typedef __attribute__((ext_vector_type(4))) short bf16x4;

#define QSCALE 0.18033688f   // 0.125 * log2(e): softmax in exp2 domain

static __device__ __forceinline__ short f2bf(float f) {
    uint32_t u = __builtin_bit_cast(uint32_t, f);
    u += 0x7fffu + ((u >> 16) & 1u);
    return (short)(u >> 16);
}
static __device__ __forceinline__ void gload16(const void* g, void* l) {
    __builtin_amdgcn_global_load_lds(
        (const __attribute__((address_space(1))) unsigned int*)g,
        (__attribute__((address_space(3))) unsigned int*)l, 16, 0, 0);
}

// ------------------------------------------------------------ prep (fused): fp32->bf16 cvt + W transpose
__global__ __launch_bounds__(256)
void prep(const float* __restrict__ xout, const float* __restrict__ xctx,
          const float* __restrict__ Wq, const float* __restrict__ Wk,
          const float* __restrict__ Wv, const float* __restrict__ Wo,
          short* __restrict__ xoutb, short* __restrict__ xctxb,
          short* __restrict__ WqT, short* __restrict__ WkT,
          short* __restrict__ WvT, short* __restrict__ WoT)
{
    __shared__ float ts[64][65];
    const int bid = blockIdx.x;
    const int tid = threadIdx.x;
    if (bid < 4096) {
        const int id = bid * 256 + tid;
        const int nA = (M_ * DIM_) / 8;
        const float* src = (id < nA) ? xout : xctx;
        short* dst = (id < nA) ? xoutb : xctxb;
        const int c = (id < nA) ? id : id - nA;
        const f32x4 v0 = *(const f32x4*)&src[(size_t)c * 8];
        const f32x4 v1 = *(const f32x4*)&src[(size_t)c * 8 + 4];
        bf16x8 o;
#pragma unroll
        for (int i = 0; i < 4; ++i) { o[i] = f2bf(v0[i]); o[4 + i] = f2bf(v1[i]); }
        *(bf16x8*)&dst[(size_t)c * 8] = o;
        return;
    }
    const int flat = bid - 4096;
    const int z = flat >> 9;
    const int rem = flat & 511;
    const int K = (z == 3) ? 2 * DIM_ : DIM_;
    const int k0 = (rem & 31) * 64;
    if (k0 >= K) return;
    const int n0 = (rem >> 5) * 64;
    const float* W = (z == 0) ? Wq : (z == 1) ? Wk : (z == 2) ? Wv : Wo;
    short* WT = (z == 0) ? WqT : (z == 1) ? WkT : (z == 2) ? WvT : WoT;
    {
        const int k = tid >> 2, noff = (tid & 3) * 16;
#pragma unroll
        for (int i = 0; i < 4; ++i)
            *(f32x4*)&ts[k][noff + i * 4] =
                *(const f32x4*)&W[(size_t)(k0 + k) * DIM_ + n0 + noff + i * 4];
    }
    __syncthreads();
    {
        const int n = tid >> 2, koff = (tid & 3) * 16;
#pragma unroll
        for (int c = 0; c < 2; ++c) {
            bf16x8 o;
#pragma unroll
            for (int i = 0; i < 8; ++i) o[i] = f2bf(ts[koff + c * 8 + i][n]);
            *(bf16x8*)&WT[(size_t)(n0 + n) * K + k0 + koff + c * 8] = o;
        }
    }
}

// ------------------------------------------------------------ QKV GEMM (MFMA, gload_lds, BK=64, XOR-swizzled LDS)
__global__ __launch_bounds__(256)
void qkv_mfma(const short* __restrict__ xoutb, const short* __restrict__ xctxb,
              const short* __restrict__ WqT, const short* __restrict__ WkT,
              const short* __restrict__ WvT,
              const float* __restrict__ bq, const float* __restrict__ bk,
              const float* __restrict__ bv,
              short* __restrict__ qh, short* __restrict__ kh, short* __restrict__ vT)
{
    const int z = blockIdx.z;
    const short* A  = (z == 0) ? xoutb : xctxb;
    const short* Bt = (z == 0) ? WqT : (z == 1) ? WkT : WvT;
    const float* bias = (z == 0) ? bq : (z == 1) ? bk : bv;

    const int flat = blockIdx.y * 8 + blockIdx.x;
    const int wgs = (flat & 7) * 32 + (flat >> 3);
    const int col0 = (wgs & 7) * 128;
    const int row0 = (wgs >> 3) * 128;
    const int tid = threadIdx.x;
    const int lane = tid & 63;
    const int w = tid >> 6;
    const int wm = (w >> 1) * 64, wn = (w & 1) * 64;
    const int l15 = lane & 15, g = lane >> 4;
    const int sub = lane >> 3, slt = lane & 7;

    __shared__ short As[128 * 64];
    __shared__ short Bs[128 * 64];

    const short* pA[4]; const short* pB[4]; short* ldsA[4]; short* ldsB[4];
#pragma unroll
    for (int i = 0; i < 4; ++i) {
        const int r = w * 32 + i * 8 + sub;
        const int sc = ((slt ^ (r & 7)) * 8);
        pA[i] = A  + (size_t)(row0 + r) * DIM_ + sc;
        pB[i] = Bt + (size_t)(col0 + r) * DIM_ + sc;
        ldsA[i] = &As[(w * 32 + i * 8) * 64];
        ldsB[i] = &Bs[(w * 32 + i * 8) * 64];
    }

    f32x4 acc[4][4];
#pragma unroll
    for (int mi = 0; mi < 4; ++mi)
#pragma unroll
        for (int ni = 0; ni < 4; ++ni) acc[mi][ni] = (f32x4)0.f;

    for (int k0 = 0; k0 < DIM_; k0 += 64) {
#pragma unroll
        for (int i = 0; i < 4; ++i) {
            gload16(pA[i] + k0, ldsA[i]);
            gload16(pB[i] + k0, ldsB[i]);
        }
        __syncthreads();
        bf16x8 af[4][2], bfr[4][2];
#pragma unroll
        for (int mi = 0; mi < 4; ++mi) {
            const int wa = wm + mi * 16 + l15;
#pragma unroll
            for (int ks = 0; ks < 2; ++ks)
                af[mi][ks] = *(const bf16x8*)&As[wa * 64 + (((ks * 4 + g) ^ (wa & 7)) * 8)];
        }
#pragma unroll
        for (int ni = 0; ni < 4; ++ni) {
            const int wb = wn + ni * 16 + l15;
#pragma unroll
            for (int ks = 0; ks < 2; ++ks)
                bfr[ni][ks] = *(const bf16x8*)&Bs[wb * 64 + (((ks * 4 + g) ^ (wb & 7)) * 8)];
        }
        __builtin_amdgcn_s_setprio(1);
#pragma unroll
        for (int mi = 0; mi < 4; ++mi)
#pragma unroll
            for (int ni = 0; ni < 4; ++ni)
#pragma unroll
                for (int ks = 0; ks < 2; ++ks)
                    acc[mi][ni] = __builtin_amdgcn_mfma_f32_16x16x32_bf16(af[mi][ks], bfr[ni][ks], acc[mi][ni], 0, 0, 0);
        __builtin_amdgcn_s_setprio(0);
        __syncthreads();
    }

#pragma unroll
    for (int ni = 0; ni < 4; ++ni) {
        const int col = col0 + wn + ni * 16 + l15;
        const int h = col >> 6, dk = col & 63;
        const float bb = bias[col];
#pragma unroll
        for (int mi = 0; mi < 4; ++mi) {
            const int rowb = row0 + wm + mi * 16 + g * 4;
            const int b = rowb >> 11;
            const int l = rowb & (L_ - 1);
            const int bh = b * 16 + h;
            if (z == 2) {
                bf16x4 o;
#pragma unroll
                for (int r = 0; r < 4; ++r) o[r] = f2bf(acc[mi][ni][r] + bb);
                *(bf16x4*)&vT[(size_t)(bh * 64 + dk) * L_ + l] = o;
            } else {
                short* dst = (z == 0) ? qh : kh;
                const float sc = (z == 0) ? QSCALE : 1.0f;
#pragma unroll
                for (int r = 0; r < 4; ++r)
                    dst[((size_t)bh * L_ + l + r) * DK_ + dk] = f2bf((acc[mi][ni][r] + bb) * sc);
            }
        }
    }
}

// ------------------------------------------------------------ fused attention v10
// Pass 1: 4-deep K pipeline (round-8, proven). Pass 2: K AND V prefetched a full
// iteration ahead (dbuf each) -> ONE barrier + one vmcnt(8) per iter; Psb is
// intra-wave (swizzled 64x64, lgkmcnt-only). LDS exactly 40960 B (4 blocks/CU).
__global__ __launch_bounds__(512, 8)
void attn_mfma(const short* __restrict__ qh, const short* __restrict__ kh,
               const short* __restrict__ vT,
               float* __restrict__ attn, short* __restrict__ ctxTb)
{
    const int bid = blockIdx.x;
    const int wg = (bid & 7) * 128 + (bid >> 3);      // XCD-contiguous
    const int bh = wg >> 5;
    const int q0 = (wg & 31) * 64;

    const int tid = threadIdx.x;
    const int lane = tid & 63;
    const int w = tid >> 6;
    const int wq = w >> 1, wk = w & 1;
    const int l15 = lane & 15, g = lane >> 4;

    // arena (shorts): bufs 0..3 at 0,4096,8192,12288 (8KB each);
    // Psb = swizzled 64x64 bf16 at 16384 (8KB region used: 4096 shorts); stat aliased on Psb.
    __shared__ short SM[20480];                        // 40960 B exactly
    short* const Kb0 = SM;
    short* const Kb1 = SM + 4096;
    short* const Vb0 = SM + 8192;
    short* const Vb1 = SM + 12288;
    char*  const PsB = (char*)(SM + 16384);            // byte-addressed, swizzled
    float* const stat = (float*)(SM + 16384);          // aliased (used only at transition)

    const short* kbase = kh + (size_t)bh * (L_ * DK_);
    const short* vbase = vT + (size_t)bh * (DK_ * L_);

    const int lr = lane >> 3, ls = lane & 7;
    const int srow = w * 8 + lr;
    const short* kSrc = kbase + (size_t)srow * DK_ + ((ls ^ (srow & 7)) * 8);
    const short* vSrc = vbase + (size_t)srow * L_ + ((ls ^ (srow & 7)) * 8);

    bf16x8 qf[2];
#pragma unroll
    for (int ks = 0; ks < 2; ++ks)
        qf[ks] = *(const bf16x8*)&qh[((size_t)bh * L_ + q0 + wq * 16 + l15) * DK_ + ks * 32 + g * 8];

    int kbOff[2][2], vbOff[4];
#pragma unroll
    for (int cc = 0; cc < 2; ++cc)
#pragma unroll
        for (int ks = 0; ks < 2; ++ks) {
            const int row = wk * 32 + cc * 16 + l15;
            kbOff[cc][ks] = row * 64 + (((ks * 4 + g) ^ (row & 7)) * 8);
        }
#pragma unroll
    for (int nf = 0; nf < 4; ++nf) {
        const int row = nf * 16 + l15;
        vbOff[nf] = row * 64 + (((wk * 4 + g) ^ (row & 7)) * 8);
    }
    // Psb byte addressing (XOR swizzle within 128B row)
    const int psW0 = (wq * 16 + g * 4) * 128;                 // write row base (r adds 128)
    const int psWc = (wk * 32 + l15) * 2;                     // write col bytes (cc adds 32)
    const int psRrow = wq * 16 + l15;
    const int psRaddr = psRrow * 128 + (((wk * 64 + g * 16)) ^ ((psRrow & 7) << 4));

    // ---------------- pass 1: online stats, 4-deep K pipeline (round-8 verbatim)
    float m[4], s[4];
#pragma unroll
    for (int r = 0; r < 4; ++r) { m[r] = -1e30f; s[r] = 0.f; }

#pragma unroll
    for (int i = 0; i < 3; ++i)
        gload16(kSrc + (size_t)i * 64 * DK_, SM + (i << 12) + w * 512);
    asm volatile("s_waitcnt vmcnt(2)" ::: "memory");
    __builtin_amdgcn_sched_barrier(0);
    __builtin_amdgcn_s_barrier();

    for (int t = 0; t < 32; ++t) {
        if (t < 29)
            gload16(kSrc + (size_t)(t + 3) * 64 * DK_, SM + (((t + 3) & 3) << 12) + w * 512);
        const short* kb = SM + ((t & 3) << 12);
        f32x4 sa[2];
#pragma unroll
        for (int cc = 0; cc < 2; ++cc) sa[cc] = (f32x4)0.f;
        __builtin_amdgcn_s_setprio(1);
#pragma unroll
        for (int cc = 0; cc < 2; ++cc)
#pragma unroll
            for (int ks = 0; ks < 2; ++ks)
                sa[cc] = __builtin_amdgcn_mfma_f32_16x16x32_bf16(qf[ks], *(const bf16x8*)&kb[kbOff[cc][ks]], sa[cc], 0, 0, 0);
        __builtin_amdgcn_s_setprio(0);
#pragma unroll
        for (int r = 0; r < 4; ++r) {
            const float tm = fmaxf(sa[0][r], sa[1][r]);
            const float mn = fmaxf(m[r], tm);
            s[r] = s[r] * exp2f(m[r] - mn) + exp2f(sa[0][r] - mn) + exp2f(sa[1][r] - mn);
            m[r] = mn;
        }
        if (t < 29)       { asm volatile("s_waitcnt vmcnt(2)" ::: "memory"); }
        else if (t == 29) { asm volatile("s_waitcnt vmcnt(1)" ::: "memory"); }
        else if (t == 30) { asm volatile("s_waitcnt vmcnt(0)" ::: "memory"); }
        __builtin_amdgcn_sched_barrier(0);
        if (t < 31) __builtin_amdgcn_s_barrier();
    }
#pragma unroll
    for (int mask = 1; mask <= 8; mask <<= 1) {
#pragma unroll
        for (int r = 0; r < 4; ++r) {
            const float mo = __shfl_xor(m[r], mask);
            const float so = __shfl_xor(s[r], mask);
            const float mn = fmaxf(m[r], mo);
            s[r] = s[r] * exp2f(m[r] - mn) + so * exp2f(mo - mn);
            m[r] = mn;
        }
    }
    if (l15 == 0) {
#pragma unroll
        for (int r = 0; r < 4; ++r) {
            stat[((wq * 2 + wk) * 16 + g * 4 + r) * 2 + 0] = m[r];
            stat[((wq * 2 + wk) * 16 + g * 4 + r) * 2 + 1] = s[r];
        }
    }
    // prologue for pass 2: K(0)->buf0, V(0)->buf2 (last read t=28/t=30, barrier-safe)
    gload16(kSrc, Kb0 + w * 512);
    gload16(vSrc, Vb0 + w * 512);
    asm volatile("s_waitcnt lgkmcnt(0)" ::: "memory");   // stat visible
    __builtin_amdgcn_s_barrier();
    float inv_s[4];
#pragma unroll
    for (int r = 0; r < 4; ++r) {
        const float m0 = stat[((wq * 2 + 0) * 16 + g * 4 + r) * 2 + 0];
        const float s0 = stat[((wq * 2 + 0) * 16 + g * 4 + r) * 2 + 1];
        const float m1 = stat[((wq * 2 + 1) * 16 + g * 4 + r) * 2 + 0];
        const float s1 = stat[((wq * 2 + 1) * 16 + g * 4 + r) * 2 + 1];
        const float mn = fmaxf(m0, m1);
        m[r] = mn;
        inv_s[r] = 1.0f / (s0 * exp2f(m0 - mn) + s1 * exp2f(m1 - mn));
    }

    f32x4 cacc[4];
#pragma unroll
    for (int nf = 0; nf < 4; ++nf) cacc[nf] = (f32x4)0.f;

    float* attnB = attn + ((size_t)bh * L_ + q0) * L_;

    asm volatile("s_waitcnt vmcnt(0)" ::: "memory");   // K(0),V(0) landed
    __builtin_amdgcn_sched_barrier(0);
    __builtin_amdgcn_s_barrier();                      // also fences stat reads vs Psb writes

    // ---------------- pass 2: ONE barrier/iter; K,V prefetched a full iter ahead
    // per-iter vmem issue order: K(t+1), V(t+1), stores(t)x8
    for (int t = 0; t < 32; ++t) {
        if (t) {
            asm volatile("s_waitcnt vmcnt(8)" ::: "memory");   // K(t),V(t) landed; 8 stores fly
            __builtin_amdgcn_sched_barrier(0);
            __builtin_amdgcn_s_barrier();
        }
        if (t < 31) {
            gload16(kSrc + (size_t)(t + 1) * 64 * DK_, ((t & 1) ? Kb0 : Kb1) + w * 512);
            gload16(vSrc + (t + 1) * 64, ((t & 1) ? Vb0 : Vb1) + w * 512);
        }
        const short* kb = (t & 1) ? Kb1 : Kb0;
        const short* vb = (t & 1) ? Vb1 : Vb0;
        f32x4 sa[2];
#pragma unroll
        for (int cc = 0; cc < 2; ++cc) sa[cc] = (f32x4)0.f;
        __builtin_amdgcn_s_setprio(1);
#pragma unroll
        for (int cc = 0; cc < 2; ++cc)
#pragma unroll
            for (int ks = 0; ks < 2; ++ks)
                sa[cc] = __builtin_amdgcn_mfma_f32_16x16x32_bf16(qf[ks], *(const bf16x8*)&kb[kbOff[cc][ks]], sa[cc], 0, 0, 0);
        __builtin_amdgcn_s_setprio(0);
#pragma unroll
        for (int cc = 0; cc < 2; ++cc)
#pragma unroll
            for (int r = 0; r < 4; ++r) {
                const float p = exp2f(sa[cc][r] - m[r]) * inv_s[r];
                const int rrow = wq * 16 + g * 4 + r;
                *(short*)(PsB + rrow * 128 + (((psWc + cc * 32)) ^ ((rrow & 7) << 4))) = f2bf(p);
                __builtin_nontemporal_store(
                    p, attnB + (size_t)rrow * L_ + t * 64 + wk * 32 + cc * 16 + l15);
            }
        asm volatile("s_waitcnt lgkmcnt(0)" ::: "memory");   // own Psb writes done (intra-wave)
        __builtin_amdgcn_sched_barrier(0);
        const bf16x8 pa = *(const bf16x8*)(PsB + psRaddr);
        __builtin_amdgcn_s_setprio(1);
#pragma unroll
        for (int nf = 0; nf < 4; ++nf)
            cacc[nf] = __builtin_amdgcn_mfma_f32_16x16x32_bf16(pa, *(const bf16x8*)&vb[vbOff[nf]], cacc[nf], 0, 0, 0);
        __builtin_amdgcn_s_setprio(0);
    }

    // epilogue: combine kv-halves, store ctx^T bf16
    __syncthreads();
    float* scr = (float*)Kb0;
    float* scr1 = (float*)Kb1;
    if (wk) {
#pragma unroll
        for (int nf = 0; nf < 4; ++nf) {
            float* p = (nf < 2) ? scr : scr1;
            *(f32x4*)&p[(((wq * 2) + (nf & 1)) * 64 + lane) * 4] = cacc[nf];
        }
    }
    __syncthreads();
    if (!wk) {
#pragma unroll
        for (int nf = 0; nf < 4; ++nf) {
            const float* p = (nf < 2) ? scr : scr1;
            const f32x4 o = cacc[nf] + *(const f32x4*)&p[(((wq * 2) + (nf & 1)) * 64 + lane) * 4];
            bf16x4 ob;
#pragma unroll
            for (int r = 0; r < 4; ++r) ob[r] = f2bf(o[r]);
            *(bf16x4*)&ctxTb[(size_t)(bh * 64 + nf * 16 + l15) * L_ + q0 + wq * 16 + g * 4] = ob;
        }
    }
}

// ------------------------------------------------------------ output projection (MFMA, BM=128 BN=64, 2 blocks/CU)
__global__ __launch_bounds__(256)
void out_mfma(const short* __restrict__ ctxTb, const short* __restrict__ xoutb,
              const short* __restrict__ WoT, const float* __restrict__ bo,
              float* __restrict__ out)
{
    const int flat = blockIdx.y * 16 + blockIdx.x;
    const int wgs = (flat & 7) * 64 + (flat >> 3);
    const int col0 = (wgs & 15) * 64;
    const int row0 = (wgs >> 4) * 128;
    const int tid = threadIdx.x;
    const int lane = tid & 63;
    const int w = tid >> 6;
    const int wm = (w >> 1) * 64, wn = (w & 1) * 32;
    const int l15 = lane & 15, g = lane >> 4;
    const int sub = lane >> 3, slt = lane & 7;

    __shared__ short As[128 * 64];
    __shared__ short Bs[64 * 64];

    const short* pA1[4]; const short* pA2[4]; const short* pB[2];
    short* ldsA[4]; short* ldsB[2];
#pragma unroll
    for (int i = 0; i < 4; ++i) {
        const int r = w * 32 + i * 8 + sub;
        const int rr = row0 + r;
        const int b = rr >> 11, l_ = rr & (L_ - 1);
        const int bh = b * 16 + (l_ >> 7), d = (l_ & 127) >> 1;
        const size_t off1 = ((size_t)(bh * 64 + d) << 11) + (size_t)((l_ & 1) << 10);
        const int sc = ((slt ^ (r & 7)) * 8);
        pA1[i] = ctxTb + off1 + sc;
        pA2[i] = xoutb + (size_t)rr * DIM_ + sc;
        ldsA[i] = &As[(w * 32 + i * 8) * 64];
    }
#pragma unroll
    for (int i = 0; i < 2; ++i) {
        const int r = w * 16 + i * 8 + sub;
        const int sc = ((slt ^ (r & 7)) * 8);
        pB[i]  = WoT + (size_t)(col0 + r) * (2 * DIM_) + sc;
        ldsB[i] = &Bs[(w * 16 + i * 8) * 64];
    }

    f32x4 acc[4][2];
#pragma unroll
    for (int mi = 0; mi < 4; ++mi)
#pragma unroll
        for (int ni = 0; ni < 2; ++ni) acc[mi][ni] = (f32x4)0.f;

    for (int k0 = 0; k0 < 2 * DIM_; k0 += 64) {
        const bool first = (k0 < DIM_);
        const int kk = first ? k0 : k0 - DIM_;
#pragma unroll
        for (int i = 0; i < 4; ++i)
            gload16(first ? (pA1[i] + kk) : (pA2[i] + kk), ldsA[i]);
#pragma unroll
        for (int i = 0; i < 2; ++i)
            gload16(pB[i] + k0, ldsB[i]);
        __syncthreads();
        bf16x8 af[4][2], bfr[2][2];
#pragma unroll
        for (int mi = 0; mi < 4; ++mi) {
            const int wa = wm + mi * 16 + l15;
#pragma unroll
            for (int ks = 0; ks < 2; ++ks)
                af[mi][ks] = *(const bf16x8*)&As[wa * 64 + (((ks * 4 + g) ^ (wa & 7)) * 8)];
        }
#pragma unroll
        for (int ni = 0; ni < 2; ++ni) {
            const int wb = wn + ni * 16 + l15;
#pragma unroll
            for (int ks = 0; ks < 2; ++ks)
                bfr[ni][ks] = *(const bf16x8*)&Bs[wb * 64 + (((ks * 4 + g) ^ (wb & 7)) * 8)];
        }
        __builtin_amdgcn_s_setprio(1);
#pragma unroll
        for (int mi = 0; mi < 4; ++mi)
#pragma unroll
            for (int ni = 0; ni < 2; ++ni)
#pragma unroll
                for (int ks = 0; ks < 2; ++ks)
                    acc[mi][ni] = __builtin_amdgcn_mfma_f32_16x16x32_bf16(af[mi][ks], bfr[ni][ks], acc[mi][ni], 0, 0, 0);
        __builtin_amdgcn_s_setprio(0);
        __syncthreads();
    }

#pragma unroll
    for (int ni = 0; ni < 2; ++ni) {
        const int col = col0 + wn + ni * 16 + l15;
        const float bb = bo[col];
#pragma unroll
        for (int mi = 0; mi < 4; ++mi) {
            const int rowb = row0 + wm + mi * 16 + g * 4;
#pragma unroll
            for (int r = 0; r < 4; ++r)
                out[(size_t)(rowb + r) * DIM_ + col] = tanhf(acc[mi][ni][r] + bb);
        }
    }
}

// ------------------------------------------------------------ launch
extern "C" void kernel_launch(void* const* d_in, const int* in_sizes, int n_in,
                              void* d_out, int out_size, void* d_ws, size_t ws_size,
                              hipStream_t stream)
{
    const float* xout = (const float*)d_in[0];
    const float* xctx = (const float*)d_in[1];
    const float* Wq = (const float*)d_in[2];
    const float* bq = (const float*)d_in[3];
    const float* Wk = (const float*)d_in[4];
    const float* bk = (const float*)d_in[5];
    const float* Wv = (const float*)d_in[6];
    const float* bv = (const float*)d_in[7];
    const float* Wo = (const float*)d_in[8];
    const float* bo = (const float*)d_in[9];

    float* out  = (float*)d_out;
    float* attn = out + (size_t)M_ * DIM_;

    short* ws = (short*)d_ws;
    short* xoutb = ws;
    short* xctxb = xoutb + (size_t)M_ * DIM_;
    short* WqT   = xctxb + (size_t)M_ * DIM_;
    short* WkT   = WqT + (size_t)DIM_ * DIM_;
    short* WvT   = WkT + (size_t)DIM_ * DIM_;
    short* WoT   = WvT + (size_t)DIM_ * DIM_;
    short* qh    = WoT + (size_t)2 * DIM_ * DIM_;
    short* kh    = qh + (size_t)BH_ * L_ * DK_;
    short* vT    = kh + (size_t)BH_ * L_ * DK_;
    short* ctxTb = vT + (size_t)BH_ * L_ * DK_;

    prep<<<6144, 256, 0, stream>>>(xout, xctx, Wq, Wk, Wv, Wo,
                                   xoutb, xctxb, WqT, WkT, WvT, WoT);
    qkv_mfma<<<dim3(8, 32, 3), 256, 0, stream>>>(
        xoutb, xctxb, WqT, WkT, WvT, bq, bk, bv, qh, kh, vT);
    attn_mfma<<<1024, 512, 0, stream>>>(qh, kh, vT, attn, ctxTb);
    out_mfma<<<dim3(16, 32), 256, 0, stream>>>(ctxTb, xoutb, WoT, bo, out);
}

// Round 13
// 281.984 us; speedup vs baseline: 1.5721x; 1.0732x over previous
//
#include <hip/hip_runtime.h>
#include <math.h>
#include <stdint.h>

#define DIM_ 1024
#define HEADS_ 16
#define DK_ 64
#define B_ 2
#define L_ 2048
#define BH_ (B_*HEADS_)
#define M_ (B_*L_)

typedef __attribute__((ext_vector_type(4))) float f32x4;
typedef __attribute__((ext_vector_type(8))) short bf16x8;
typedef __attribute__((ext_vector_type(4))) short bf16x4;

#define QSCALE 0.18033688f   // 0.125 * log2(e): softmax in exp2 domain

static __device__ __forceinline__ short f2bf(float f) {
    uint32_t u = __builtin_bit_cast(uint32_t, f);
    u += 0x7fffu + ((u >> 16) & 1u);
    return (short)(u >> 16);
}
static __device__ __forceinline__ void gload16(const void* g, void* l) {
    __builtin_amdgcn_global_load_lds(
        (const __attribute__((address_space(1))) unsigned int*)g,
        (__attribute__((address_space(3))) unsigned int*)l, 16, 0, 0);
}

// ------------------------------------------------------------ prep (fused): fp32->bf16 cvt + W transpose
__global__ __launch_bounds__(256)
void prep(const float* __restrict__ xout, const float* __restrict__ xctx,
          const float* __restrict__ Wq, const float* __restrict__ Wk,
          const float* __restrict__ Wv, const float* __restrict__ Wo,
          short* __restrict__ xoutb, short* __restrict__ xctxb,
          short* __restrict__ WqT, short* __restrict__ WkT,
          short* __restrict__ WvT, short* __restrict__ WoT)
{
    __shared__ float ts[64][65];
    const int bid = blockIdx.x;
    const int tid = threadIdx.x;
    if (bid < 4096) {
        const int id = bid * 256 + tid;
        const int nA = (M_ * DIM_) / 8;
        const float* src = (id < nA) ? xout : xctx;
        short* dst = (id < nA) ? xoutb : xctxb;
        const int c = (id < nA) ? id : id - nA;
        const f32x4 v0 = *(const f32x4*)&src[(size_t)c * 8];
        const f32x4 v1 = *(const f32x4*)&src[(size_t)c * 8 + 4];
        bf16x8 o;
#pragma unroll
        for (int i = 0; i < 4; ++i) { o[i] = f2bf(v0[i]); o[4 + i] = f2bf(v1[i]); }
        *(bf16x8*)&dst[(size_t)c * 8] = o;
        return;
    }
    const int flat = bid - 4096;
    const int z = flat >> 9;
    const int rem = flat & 511;
    const int K = (z == 3) ? 2 * DIM_ : DIM_;
    const int k0 = (rem & 31) * 64;
    if (k0 >= K) return;
    const int n0 = (rem >> 5) * 64;
    const float* W = (z == 0) ? Wq : (z == 1) ? Wk : (z == 2) ? Wv : Wo;
    short* WT = (z == 0) ? WqT : (z == 1) ? WkT : (z == 2) ? WvT : WoT;
    {
        const int k = tid >> 2, noff = (tid & 3) * 16;
#pragma unroll
        for (int i = 0; i < 4; ++i)
            *(f32x4*)&ts[k][noff + i * 4] =
                *(const f32x4*)&W[(size_t)(k0 + k) * DIM_ + n0 + noff + i * 4];
    }
    __syncthreads();
    {
        const int n = tid >> 2, koff = (tid & 3) * 16;
#pragma unroll
        for (int c = 0; c < 2; ++c) {
            bf16x8 o;
#pragma unroll
            for (int i = 0; i < 8; ++i) o[i] = f2bf(ts[koff + c * 8 + i][n]);
            *(bf16x8*)&WT[(size_t)(n0 + n) * K + k0 + koff + c * 8] = o;
        }
    }
}

// ------------------------------------------------------------ QKV GEMM v2: 2-phase pipeline
// stage(k+1) issued BEFORE compute(k); one vmcnt(0)+s_barrier per k-step (T3-min).
__global__ __launch_bounds__(256)
void qkv_mfma(const short* __restrict__ xoutb, const short* __restrict__ xctxb,
              const short* __restrict__ WqT, const short* __restrict__ WkT,
              const short* __restrict__ WvT,
              const float* __restrict__ bq, const float* __restrict__ bk,
              const float* __restrict__ bv,
              short* __restrict__ qh, short* __restrict__ kh, short* __restrict__ vT)
{
    const int z = blockIdx.z;
    const short* A  = (z == 0) ? xoutb : xctxb;
    const short* Bt = (z == 0) ? WqT : (z == 1) ? WkT : WvT;
    const float* bias = (z == 0) ? bq : (z == 1) ? bk : bv;

    const int flat = blockIdx.y * 8 + blockIdx.x;
    const int wgs = (flat & 7) * 32 + (flat >> 3);
    const int col0 = (wgs & 7) * 128;
    const int row0 = (wgs >> 3) * 128;
    const int tid = threadIdx.x;
    const int lane = tid & 63;
    const int w = tid >> 6;
    const int wm = (w >> 1) * 64, wn = (w & 1) * 64;
    const int l15 = lane & 15, g = lane >> 4;
    const int sub = lane >> 3, slt = lane & 7;

    __shared__ short As[2 * 128 * 64];   // 32 KB (double-buffered)
    __shared__ short Bs[2 * 128 * 64];   // 32 KB

    const short* pA[4]; const short* pB[4]; int ldsOff[4];
#pragma unroll
    for (int i = 0; i < 4; ++i) {
        const int r = w * 32 + i * 8 + sub;
        const int sc = ((slt ^ (r & 7)) * 8);
        pA[i] = A  + (size_t)(row0 + r) * DIM_ + sc;
        pB[i] = Bt + (size_t)(col0 + r) * DIM_ + sc;
        ldsOff[i] = (w * 32 + i * 8) * 64;
    }

    f32x4 acc[4][4];
#pragma unroll
    for (int mi = 0; mi < 4; ++mi)
#pragma unroll
        for (int ni = 0; ni < 4; ++ni) acc[mi][ni] = (f32x4)0.f;

#define QKV_STAGE(koff, buf)                                        \
    {                                                               \
        _Pragma("unroll")                                           \
        for (int i = 0; i < 4; ++i) {                               \
            gload16(pA[i] + (koff), As + (buf) * 8192 + ldsOff[i]); \
            gload16(pB[i] + (koff), Bs + (buf) * 8192 + ldsOff[i]); \
        }                                                           \
    }

#define QKV_COMPUTE(buf)                                                              \
    {                                                                                 \
        const short* as = As + (buf) * 8192;                                          \
        const short* bs = Bs + (buf) * 8192;                                          \
        bf16x8 af[4][2], bfr[4][2];                                                   \
        _Pragma("unroll")                                                             \
        for (int mi = 0; mi < 4; ++mi) {                                              \
            const int wa = wm + mi * 16 + l15;                                        \
            _Pragma("unroll")                                                         \
            for (int ks = 0; ks < 2; ++ks)                                            \
                af[mi][ks] = *(const bf16x8*)&as[wa * 64 + (((ks * 4 + g) ^ (wa & 7)) * 8)]; \
        }                                                                             \
        _Pragma("unroll")                                                             \
        for (int ni = 0; ni < 4; ++ni) {                                              \
            const int wb = wn + ni * 16 + l15;                                        \
            _Pragma("unroll")                                                         \
            for (int ks = 0; ks < 2; ++ks)                                            \
                bfr[ni][ks] = *(const bf16x8*)&bs[wb * 64 + (((ks * 4 + g) ^ (wb & 7)) * 8)]; \
        }                                                                             \
        __builtin_amdgcn_s_setprio(1);                                                \
        _Pragma("unroll")                                                             \
        for (int mi = 0; mi < 4; ++mi)                                                \
            _Pragma("unroll")                                                         \
            for (int ni = 0; ni < 4; ++ni)                                            \
                _Pragma("unroll")                                                     \
                for (int ks = 0; ks < 2; ++ks)                                        \
                    acc[mi][ni] = __builtin_amdgcn_mfma_f32_16x16x32_bf16(af[mi][ks], bfr[ni][ks], acc[mi][ni], 0, 0, 0); \
        __builtin_amdgcn_s_setprio(0);                                                \
    }

    // prologue: stage k=0 into buf 0
    QKV_STAGE(0, 0);
    asm volatile("s_waitcnt vmcnt(0)" ::: "memory");
    __builtin_amdgcn_sched_barrier(0);
    __builtin_amdgcn_s_barrier();

    for (int kp = 0; kp < DIM_; kp += 128) {
        // phase 0: stage kp+64 -> buf1, compute buf0
        QKV_STAGE(kp + 64, 1);
        QKV_COMPUTE(0);
        asm volatile("s_waitcnt vmcnt(0)" ::: "memory");
        __builtin_amdgcn_sched_barrier(0);
        __builtin_amdgcn_s_barrier();
        // phase 1: stage kp+128 -> buf0 (if any), compute buf1
        if (kp + 128 < DIM_) {
            QKV_STAGE(kp + 128, 0);
            QKV_COMPUTE(1);
            asm volatile("s_waitcnt vmcnt(0)" ::: "memory");
            __builtin_amdgcn_sched_barrier(0);
            __builtin_amdgcn_s_barrier();
        } else {
            QKV_COMPUTE(1);
        }
    }
#undef QKV_STAGE
#undef QKV_COMPUTE

#pragma unroll
    for (int ni = 0; ni < 4; ++ni) {
        const int col = col0 + wn + ni * 16 + l15;
        const int h = col >> 6, dk = col & 63;
        const float bb = bias[col];
#pragma unroll
        for (int mi = 0; mi < 4; ++mi) {
            const int rowb = row0 + wm + mi * 16 + g * 4;
            const int b = rowb >> 11;
            const int l = rowb & (L_ - 1);
            const int bh = b * 16 + h;
            if (z == 2) {
                bf16x4 o;
#pragma unroll
                for (int r = 0; r < 4; ++r) o[r] = f2bf(acc[mi][ni][r] + bb);
                *(bf16x4*)&vT[(size_t)(bh * 64 + dk) * L_ + l] = o;
            } else {
                short* dst = (z == 0) ? qh : kh;
                const float sc = (z == 0) ? QSCALE : 1.0f;
#pragma unroll
                for (int r = 0; r < 4; ++r)
                    dst[((size_t)bh * L_ + l + r) * DK_ + dk] = f2bf((acc[mi][ni][r] + bb) * sc);
            }
        }
    }
}

// ------------------------------------------------------------ fused attention (round-8 verbatim, 279us config)
// Pass 1: 4-deep K pipeline. Pass 2: counted-vmcnt scalar stores (2 barriers/iter).
__global__ __launch_bounds__(512, 8)
void attn_mfma(const short* __restrict__ qh, const short* __restrict__ kh,
               const short* __restrict__ vT,
               float* __restrict__ attn, short* __restrict__ ctxTb)
{
    const int bid = blockIdx.x;
    const int wg = (bid & 7) * 128 + (bid >> 3);      // XCD-contiguous
    const int bh = wg >> 5;
    const int q0 = (wg & 31) * 64;

    const int tid = threadIdx.x;
    const int lane = tid & 63;
    const int w = tid >> 6;
    const int wq = w >> 1, wk = w & 1;
    const int l15 = lane & 15, g = lane >> 4;

    __shared__ short SM[17408];
    short* const Kb0 = SM;
    short* const Kb1 = SM + 4096;
    short* const Vb  = SM + 8192;
    short* const Psb = SM + 12288;                    // 64 x 72
    float* const stat = (float*)(SM + 16896);         // [4][2][16][2]

    const short* kbase = kh + (size_t)bh * (L_ * DK_);
    const short* vbase = vT + (size_t)bh * (DK_ * L_);

    const int lr = lane >> 3, ls = lane & 7;
    const int srow = w * 8 + lr;
    const short* kSrc = kbase + (size_t)srow * DK_ + ((ls ^ (srow & 7)) * 8);
    const short* vSrc = vbase + (size_t)srow * L_ + ((ls ^ (srow & 7)) * 8);

    bf16x8 qf[2];
#pragma unroll
    for (int ks = 0; ks < 2; ++ks)
        qf[ks] = *(const bf16x8*)&qh[((size_t)bh * L_ + q0 + wq * 16 + l15) * DK_ + ks * 32 + g * 8];

    int kbOff[2][2], vbOff[4];
#pragma unroll
    for (int cc = 0; cc < 2; ++cc)
#pragma unroll
        for (int ks = 0; ks < 2; ++ks) {
            const int row = wk * 32 + cc * 16 + l15;
            kbOff[cc][ks] = row * 64 + (((ks * 4 + g) ^ (row & 7)) * 8);
        }
#pragma unroll
    for (int nf = 0; nf < 4; ++nf) {
        const int row = nf * 16 + l15;
        vbOff[nf] = row * 64 + (((wk * 4 + g) ^ (row & 7)) * 8);
    }

    // ---------------- pass 1: online stats, 4-deep K pipeline
    float m[4], s[4];
#pragma unroll
    for (int r = 0; r < 4; ++r) { m[r] = -1e30f; s[r] = 0.f; }

#pragma unroll
    for (int i = 0; i < 3; ++i)
        gload16(kSrc + (size_t)i * 64 * DK_, SM + (i << 12) + w * 512);
    asm volatile("s_waitcnt vmcnt(2)" ::: "memory");
    __builtin_amdgcn_sched_barrier(0);
    __builtin_amdgcn_s_barrier();

    for (int t = 0; t < 32; ++t) {
        if (t < 29)
            gload16(kSrc + (size_t)(t + 3) * 64 * DK_, SM + (((t + 3) & 3) << 12) + w * 512);
        const short* kb = SM + ((t & 3) << 12);
        f32x4 sa[2];
#pragma unroll
        for (int cc = 0; cc < 2; ++cc) sa[cc] = (f32x4)0.f;
        __builtin_amdgcn_s_setprio(1);
#pragma unroll
        for (int cc = 0; cc < 2; ++cc)
#pragma unroll
            for (int ks = 0; ks < 2; ++ks)
                sa[cc] = __builtin_amdgcn_mfma_f32_16x16x32_bf16(qf[ks], *(const bf16x8*)&kb[kbOff[cc][ks]], sa[cc], 0, 0, 0);
        __builtin_amdgcn_s_setprio(0);
#pragma unroll
        for (int r = 0; r < 4; ++r) {
            const float tm = fmaxf(sa[0][r], sa[1][r]);
            const float mn = fmaxf(m[r], tm);
            s[r] = s[r] * exp2f(m[r] - mn) + exp2f(sa[0][r] - mn) + exp2f(sa[1][r] - mn);
            m[r] = mn;
        }
        if (t < 29)       { asm volatile("s_waitcnt vmcnt(2)" ::: "memory"); }
        else if (t == 29) { asm volatile("s_waitcnt vmcnt(1)" ::: "memory"); }
        else if (t == 30) { asm volatile("s_waitcnt vmcnt(0)" ::: "memory"); }
        __builtin_amdgcn_sched_barrier(0);
        if (t < 31) __builtin_amdgcn_s_barrier();
    }
#pragma unroll
    for (int mask = 1; mask <= 8; mask <<= 1) {
#pragma unroll
        for (int r = 0; r < 4; ++r) {
            const float mo = __shfl_xor(m[r], mask);
            const float so = __shfl_xor(s[r], mask);
            const float mn = fmaxf(m[r], mo);
            s[r] = s[r] * exp2f(m[r] - mn) + so * exp2f(mo - mn);
            m[r] = mn;
        }
    }
    if (l15 == 0) {
#pragma unroll
        for (int r = 0; r < 4; ++r) {
            stat[((wq * 2 + wk) * 16 + g * 4 + r) * 2 + 0] = m[r];
            stat[((wq * 2 + wk) * 16 + g * 4 + r) * 2 + 1] = s[r];
        }
    }
    gload16(kSrc, SM + w * 512);                       // K(0) for pass 2 -> Kb0
    asm volatile("s_waitcnt lgkmcnt(0)" ::: "memory"); // stat visible
    __builtin_amdgcn_s_barrier();
    float inv_s[4];
#pragma unroll
    for (int r = 0; r < 4; ++r) {
        const float m0 = stat[((wq * 2 + 0) * 16 + g * 4 + r) * 2 + 0];
        const float s0 = stat[((wq * 2 + 0) * 16 + g * 4 + r) * 2 + 1];
        const float m1 = stat[((wq * 2 + 1) * 16 + g * 4 + r) * 2 + 0];
        const float s1 = stat[((wq * 2 + 1) * 16 + g * 4 + r) * 2 + 1];
        const float mn = fmaxf(m0, m1);
        m[r] = mn;
        inv_s[r] = 1.0f / (s0 * exp2f(m0 - mn) + s1 * exp2f(m1 - mn));
    }

    f32x4 cacc[4];
#pragma unroll
    for (int nf = 0; nf < 4; ++nf) cacc[nf] = (f32x4)0.f;

    float* attnB = attn + ((size_t)bh * L_ + q0) * L_;

    asm volatile("s_waitcnt vmcnt(0)" ::: "memory");   // K(0) landed
    __builtin_amdgcn_sched_barrier(0);
    __builtin_amdgcn_s_barrier();

    // ---------------- pass 2: recompute, fp32 register attn stores, PV
    for (int t = 0; t < 32; ++t) {
        if (t) {
            asm volatile("s_waitcnt vmcnt(8)" ::: "memory");   // K(t) landed; stores keep flying
            __builtin_amdgcn_sched_barrier(0);
            __builtin_amdgcn_s_barrier();
        }
        gload16(vSrc + t * 64, Vb + w * 512);                   // V(t)
        {
            const int tn = (t < 31) ? t + 1 : t;                // uniform issue count
            gload16(kSrc + (size_t)tn * 64 * DK_, ((t & 1) ? Kb0 : Kb1) + w * 512);
        }
        const short* kb = (t & 1) ? Kb1 : Kb0;
        f32x4 sa[2];
#pragma unroll
        for (int cc = 0; cc < 2; ++cc) sa[cc] = (f32x4)0.f;
        __builtin_amdgcn_s_setprio(1);
#pragma unroll
        for (int cc = 0; cc < 2; ++cc)
#pragma unroll
            for (int ks = 0; ks < 2; ++ks)
                sa[cc] = __builtin_amdgcn_mfma_f32_16x16x32_bf16(qf[ks], *(const bf16x8*)&kb[kbOff[cc][ks]], sa[cc], 0, 0, 0);
        __builtin_amdgcn_s_setprio(0);
#pragma unroll
        for (int cc = 0; cc < 2; ++cc)
#pragma unroll
            for (int r = 0; r < 4; ++r) {
                const float p = exp2f(sa[cc][r] - m[r]) * inv_s[r];
                Psb[(wq * 16 + g * 4 + r) * 72 + wk * 32 + cc * 16 + l15] = f2bf(p);
                __builtin_nontemporal_store(
                    p, attnB + (size_t)(wq * 16 + g * 4 + r) * L_ + t * 64 + wk * 32 + cc * 16 + l15);
            }
        asm volatile("s_waitcnt vmcnt(9) lgkmcnt(0)" ::: "memory");
        __builtin_amdgcn_sched_barrier(0);
        __builtin_amdgcn_s_barrier();
        const bf16x8 pa = *(const bf16x8*)&Psb[(wq * 16 + l15) * 72 + wk * 32 + g * 8];
        __builtin_amdgcn_s_setprio(1);
#pragma unroll
        for (int nf = 0; nf < 4; ++nf)
            cacc[nf] = __builtin_amdgcn_mfma_f32_16x16x32_bf16(pa, *(const bf16x8*)&Vb[vbOff[nf]], cacc[nf], 0, 0, 0);
        __builtin_amdgcn_s_setprio(0);
    }

    // epilogue: combine kv-halves, store ctx^T bf16
    __syncthreads();
    float* scr = (float*)Kb0;
    float* scr1 = (float*)Kb1;
    if (wk) {
#pragma unroll
        for (int nf = 0; nf < 4; ++nf) {
            float* p = (nf < 2) ? scr : scr1;
            *(f32x4*)&p[(((wq * 2) + (nf & 1)) * 64 + lane) * 4] = cacc[nf];
        }
    }
    __syncthreads();
    if (!wk) {
#pragma unroll
        for (int nf = 0; nf < 4; ++nf) {
            const float* p = (nf < 2) ? scr : scr1;
            const f32x4 o = cacc[nf] + *(const f32x4*)&p[(((wq * 2) + (nf & 1)) * 64 + lane) * 4];
            bf16x4 ob;
#pragma unroll
            for (int r = 0; r < 4; ++r) ob[r] = f2bf(o[r]);
            *(bf16x4*)&ctxTb[(size_t)(bh * 64 + nf * 16 + l15) * L_ + q0 + wq * 16 + g * 4] = ob;
        }
    }
}

// ------------------------------------------------------------ output projection v2: 2-phase pipeline
__global__ __launch_bounds__(256)
void out_mfma(const short* __restrict__ ctxTb, const short* __restrict__ xoutb,
              const short* __restrict__ WoT, const float* __restrict__ bo,
              float* __restrict__ out)
{
    const int flat = blockIdx.y * 16 + blockIdx.x;
    const int wgs = (flat & 7) * 64 + (flat >> 3);
    const int col0 = (wgs & 15) * 64;
    const int row0 = (wgs >> 4) * 128;
    const int tid = threadIdx.x;
    const int lane = tid & 63;
    const int w = tid >> 6;
    const int wm = (w >> 1) * 64, wn = (w & 1) * 32;
    const int l15 = lane & 15, g = lane >> 4;
    const int sub = lane >> 3, slt = lane & 7;

    __shared__ short As[2 * 128 * 64];   // 32 KB
    __shared__ short Bs[2 * 64 * 64];    // 16 KB

    const short* pA1[4]; const short* pA2[4]; const short* pB[2];
    int ldsAOff[4]; int ldsBOff[2];
#pragma unroll
    for (int i = 0; i < 4; ++i) {
        const int r = w * 32 + i * 8 + sub;
        const int rr = row0 + r;
        const int b = rr >> 11, l_ = rr & (L_ - 1);
        const int bh = b * 16 + (l_ >> 7), d = (l_ & 127) >> 1;
        const size_t off1 = ((size_t)(bh * 64 + d) << 11) + (size_t)((l_ & 1) << 10);
        const int sc = ((slt ^ (r & 7)) * 8);
        pA1[i] = ctxTb + off1 + sc;
        pA2[i] = xoutb + (size_t)rr * DIM_ + sc;
        ldsAOff[i] = (w * 32 + i * 8) * 64;
    }
#pragma unroll
    for (int i = 0; i < 2; ++i) {
        const int r = w * 16 + i * 8 + sub;
        const int sc = ((slt ^ (r & 7)) * 8);
        pB[i]  = WoT + (size_t)(col0 + r) * (2 * DIM_) + sc;
        ldsBOff[i] = (w * 16 + i * 8) * 64;
    }

    f32x4 acc[4][2];
#pragma unroll
    for (int mi = 0; mi < 4; ++mi)
#pragma unroll
        for (int ni = 0; ni < 2; ++ni) acc[mi][ni] = (f32x4)0.f;

#define OUT_STAGE(koff, buf)                                                     \
    {                                                                            \
        _Pragma("unroll")                                                        \
        for (int i = 0; i < 4; ++i) {                                            \
            const short* srcA = ((koff) < DIM_) ? (pA1[i] + (koff))              \
                                                : (pA2[i] + ((koff) - DIM_));    \
            gload16(srcA, As + (buf) * 8192 + ldsAOff[i]);                       \
        }                                                                        \
        _Pragma("unroll")                                                        \
        for (int i = 0; i < 2; ++i)                                              \
            gload16(pB[i] + (koff), Bs + (buf) * 4096 + ldsBOff[i]);             \
    }

#define OUT_COMPUTE(buf)                                                              \
    {                                                                                 \
        const short* as = As + (buf) * 8192;                                          \
        const short* bs = Bs + (buf) * 4096;                                          \
        bf16x8 af[4][2], bfr[2][2];                                                   \
        _Pragma("unroll")                                                             \
        for (int mi = 0; mi < 4; ++mi) {                                              \
            const int wa = wm + mi * 16 + l15;                                        \
            _Pragma("unroll")                                                         \
            for (int ks = 0; ks < 2; ++ks)                                            \
                af[mi][ks] = *(const bf16x8*)&as[wa * 64 + (((ks * 4 + g) ^ (wa & 7)) * 8)]; \
        }                                                                             \
        _Pragma("unroll")                                                             \
        for (int ni = 0; ni < 2; ++ni) {                                              \
            const int wb = wn + ni * 16 + l15;                                        \
            _Pragma("unroll")                                                         \
            for (int ks = 0; ks < 2; ++ks)                                            \
                bfr[ni][ks] = *(const bf16x8*)&bs[wb * 64 + (((ks * 4 + g) ^ (wb & 7)) * 8)]; \
        }                                                                             \
        __builtin_amdgcn_s_setprio(1);                                                \
        _Pragma("unroll")                                                             \
        for (int mi = 0; mi < 4; ++mi)                                                \
            _Pragma("unroll")                                                         \
            for (int ni = 0; ni < 2; ++ni)                                            \
                _Pragma("unroll")                                                     \
                for (int ks = 0; ks < 2; ++ks)                                        \
                    acc[mi][ni] = __builtin_amdgcn_mfma_f32_16x16x32_bf16(af[mi][ks], bfr[ni][ks], acc[mi][ni], 0, 0, 0); \
        __builtin_amdgcn_s_setprio(0);                                                \
    }

    OUT_STAGE(0, 0);
    asm volatile("s_waitcnt vmcnt(0)" ::: "memory");
    __builtin_amdgcn_sched_barrier(0);
    __builtin_amdgcn_s_barrier();

    for (int kp = 0; kp < 2 * DIM_; kp += 128) {
        OUT_STAGE(kp + 64, 1);
        OUT_COMPUTE(0);
        asm volatile("s_waitcnt vmcnt(0)" ::: "memory");
        __builtin_amdgcn_sched_barrier(0);
        __builtin_amdgcn_s_barrier();
        if (kp + 128 < 2 * DIM_) {
            OUT_STAGE(kp + 128, 0);
            OUT_COMPUTE(1);
            asm volatile("s_waitcnt vmcnt(0)" ::: "memory");
            __builtin_amdgcn_sched_barrier(0);
            __builtin_amdgcn_s_barrier();
        } else {
            OUT_COMPUTE(1);
        }
    }
#undef OUT_STAGE
#undef OUT_COMPUTE

#pragma unroll
    for (int ni = 0; ni < 2; ++ni) {
        const int col = col0 + wn + ni * 16 + l15;
        const float bb = bo[col];
#pragma unroll
        for (int mi = 0; mi < 4; ++mi) {
            const int rowb = row0 + wm + mi * 16 + g * 4;
#pragma unroll
            for (int r = 0; r < 4; ++r)
                out[(size_t)(rowb + r) * DIM_ + col] = tanhf(acc[mi][ni][r] + bb);
        }
    }
}

// ------------------------------------------------------------ launch
extern "C" void kernel_launch(void* const* d_in, const int* in_sizes, int n_in,
                              void* d_out, int out_size, void* d_ws, size_t ws_size,
                              hipStream_t stream)
{
    const float* xout = (const float*)d_in[0];
    const float* xctx = (const float*)d_in[1];
    const float* Wq = (const float*)d_in[2];
    const float* bq = (const float*)d_in[3];
    const float* Wk = (const float*)d_in[4];
    const float* bk = (const float*)d_in[5];
    const float* Wv = (const float*)d_in[6];
    const float* bv = (const float*)d_in[7];
    const float* Wo = (const float*)d_in[8];
    const float* bo = (const float*)d_in[9];

    float* out  = (float*)d_out;
    float* attn = out + (size_t)M_ * DIM_;

    short* ws = (short*)d_ws;
    short* xoutb = ws;
    short* xctxb = xoutb + (size_t)M_ * DIM_;
    short* WqT   = xctxb + (size_t)M_ * DIM_;
    short* WkT   = WqT + (size_t)DIM_ * DIM_;
    short* WvT   = WkT + (size_t)DIM_ * DIM_;
    short* WoT   = WvT + (size_t)DIM_ * DIM_;
    short* qh    = WoT + (size_t)2 * DIM_ * DIM_;
    short* kh    = qh + (size_t)BH_ * L_ * DK_;
    short* vT    = kh + (size_t)BH_ * L_ * DK_;
    short* ctxTb = vT + (size_t)BH_ * L_ * DK_;

    prep<<<6144, 256, 0, stream>>>(xout, xctx, Wq, Wk, Wv, Wo,
                                   xoutb, xctxb, WqT, WkT, WvT, WoT);
    qkv_mfma<<<dim3(8, 32, 3), 256, 0, stream>>>(
        xoutb, xctxb, WqT, WkT, WvT, bq, bk, bv, qh, kh, vT);
    attn_mfma<<<1024, 512, 0, stream>>>(qh, kh, vT, attn, ctxTb);
    out_mfma<<<dim3(16, 32), 256, 0, stream>>>(ctxTb, xoutb, WoT, bo, out);
}

// Round 14
// 271.328 us; speedup vs baseline: 1.6338x; 1.0393x over previous
//
#include <hip/hip_runtime.h>
#include <math.h>
#include <stdint.h>

#define DIM_ 1024
#define HEADS_ 16
#define DK_ 64
#define B_ 2
#define L_ 2048
#define BH_ (B_*HEADS_)
#define M_ (B_*L_)

typedef __attribute__((ext_vector_type(4))) float f32x4;
typedef __attribute__((ext_vector_type(8))) short bf16x8;
typedef __attribute__((ext_vector_type(4))) short bf16x4;

#define QSCALE 0.18033688f   // 0.125 * log2(e): softmax in exp2 domain

static __device__ __forceinline__ short f2bf(float f) {
    uint32_t u = __builtin_bit_cast(uint32_t, f);
    u += 0x7fffu + ((u >> 16) & 1u);
    return (short)(u >> 16);
}
static __device__ __forceinline__ void gload16(const void* g, void* l) {
    __builtin_amdgcn_global_load_lds(
        (const __attribute__((address_space(1))) unsigned int*)g,
        (__attribute__((address_space(3))) unsigned int*)l, 16, 0, 0);
}

// ------------------------------------------------------------ prep (fused): fp32->bf16 cvt + W transpose
__global__ __launch_bounds__(256)
void prep(const float* __restrict__ xout, const float* __restrict__ xctx,
          const float* __restrict__ Wq, const float* __restrict__ Wk,
          const float* __restrict__ Wv, const float* __restrict__ Wo,
          short* __restrict__ xoutb, short* __restrict__ xctxb,
          short* __restrict__ WqT, short* __restrict__ WkT,
          short* __restrict__ WvT, short* __restrict__ WoT)
{
    __shared__ float ts[64][65];
    const int bid = blockIdx.x;
    const int tid = threadIdx.x;
    if (bid < 4096) {
        const int id = bid * 256 + tid;
        const int nA = (M_ * DIM_) / 8;
        const float* src = (id < nA) ? xout : xctx;
        short* dst = (id < nA) ? xoutb : xctxb;
        const int c = (id < nA) ? id : id - nA;
        const f32x4 v0 = *(const f32x4*)&src[(size_t)c * 8];
        const f32x4 v1 = *(const f32x4*)&src[(size_t)c * 8 + 4];
        bf16x8 o;
#pragma unroll
        for (int i = 0; i < 4; ++i) { o[i] = f2bf(v0[i]); o[4 + i] = f2bf(v1[i]); }
        *(bf16x8*)&dst[(size_t)c * 8] = o;
        return;
    }
    const int flat = bid - 4096;
    const int z = flat >> 9;
    const int rem = flat & 511;
    const int K = (z == 3) ? 2 * DIM_ : DIM_;
    const int k0 = (rem & 31) * 64;
    if (k0 >= K) return;
    const int n0 = (rem >> 5) * 64;
    const float* W = (z == 0) ? Wq : (z == 1) ? Wk : (z == 2) ? Wv : Wo;
    short* WT = (z == 0) ? WqT : (z == 1) ? WkT : (z == 2) ? WvT : WoT;
    {
        const int k = tid >> 2, noff = (tid & 3) * 16;
#pragma unroll
        for (int i = 0; i < 4; ++i)
            *(f32x4*)&ts[k][noff + i * 4] =
                *(const f32x4*)&W[(size_t)(k0 + k) * DIM_ + n0 + noff + i * 4];
    }
    __syncthreads();
    {
        const int n = tid >> 2, koff = (tid & 3) * 16;
#pragma unroll
        for (int c = 0; c < 2; ++c) {
            bf16x8 o;
#pragma unroll
            for (int i = 0; i < 8; ++i) o[i] = f2bf(ts[koff + c * 8 + i][n]);
            *(bf16x8*)&WT[(size_t)(n0 + n) * K + k0 + koff + c * 8] = o;
        }
    }
}

// ------------------------------------------------------------ QKV GEMM (round-8: MFMA, gload_lds, BK=64, XOR-swizzled LDS)
__global__ __launch_bounds__(256)
void qkv_mfma(const short* __restrict__ xoutb, const short* __restrict__ xctxb,
              const short* __restrict__ WqT, const short* __restrict__ WkT,
              const short* __restrict__ WvT,
              const float* __restrict__ bq, const float* __restrict__ bk,
              const float* __restrict__ bv,
              short* __restrict__ qh, short* __restrict__ kh, short* __restrict__ vT)
{
    const int z = blockIdx.z;
    const short* A  = (z == 0) ? xoutb : xctxb;
    const short* Bt = (z == 0) ? WqT : (z == 1) ? WkT : WvT;
    const float* bias = (z == 0) ? bq : (z == 1) ? bk : bv;

    const int flat = blockIdx.y * 8 + blockIdx.x;
    const int wgs = (flat & 7) * 32 + (flat >> 3);
    const int col0 = (wgs & 7) * 128;
    const int row0 = (wgs >> 3) * 128;
    const int tid = threadIdx.x;
    const int lane = tid & 63;
    const int w = tid >> 6;
    const int wm = (w >> 1) * 64, wn = (w & 1) * 64;
    const int l15 = lane & 15, g = lane >> 4;
    const int sub = lane >> 3, slt = lane & 7;

    __shared__ short As[128 * 64];
    __shared__ short Bs[128 * 64];

    const short* pA[4]; const short* pB[4]; short* ldsA[4]; short* ldsB[4];
#pragma unroll
    for (int i = 0; i < 4; ++i) {
        const int r = w * 32 + i * 8 + sub;
        const int sc = ((slt ^ (r & 7)) * 8);
        pA[i] = A  + (size_t)(row0 + r) * DIM_ + sc;
        pB[i] = Bt + (size_t)(col0 + r) * DIM_ + sc;
        ldsA[i] = &As[(w * 32 + i * 8) * 64];
        ldsB[i] = &Bs[(w * 32 + i * 8) * 64];
    }

    f32x4 acc[4][4];
#pragma unroll
    for (int mi = 0; mi < 4; ++mi)
#pragma unroll
        for (int ni = 0; ni < 4; ++ni) acc[mi][ni] = (f32x4)0.f;

    for (int k0 = 0; k0 < DIM_; k0 += 64) {
#pragma unroll
        for (int i = 0; i < 4; ++i) {
            gload16(pA[i] + k0, ldsA[i]);
            gload16(pB[i] + k0, ldsB[i]);
        }
        __syncthreads();
        bf16x8 af[4][2], bfr[4][2];
#pragma unroll
        for (int mi = 0; mi < 4; ++mi) {
            const int wa = wm + mi * 16 + l15;
#pragma unroll
            for (int ks = 0; ks < 2; ++ks)
                af[mi][ks] = *(const bf16x8*)&As[wa * 64 + (((ks * 4 + g) ^ (wa & 7)) * 8)];
        }
#pragma unroll
        for (int ni = 0; ni < 4; ++ni) {
            const int wb = wn + ni * 16 + l15;
#pragma unroll
            for (int ks = 0; ks < 2; ++ks)
                bfr[ni][ks] = *(const bf16x8*)&Bs[wb * 64 + (((ks * 4 + g) ^ (wb & 7)) * 8)];
        }
        __builtin_amdgcn_s_setprio(1);
#pragma unroll
        for (int mi = 0; mi < 4; ++mi)
#pragma unroll
            for (int ni = 0; ni < 4; ++ni)
#pragma unroll
                for (int ks = 0; ks < 2; ++ks)
                    acc[mi][ni] = __builtin_amdgcn_mfma_f32_16x16x32_bf16(af[mi][ks], bfr[ni][ks], acc[mi][ni], 0, 0, 0);
        __builtin_amdgcn_s_setprio(0);
        __syncthreads();
    }

#pragma unroll
    for (int ni = 0; ni < 4; ++ni) {
        const int col = col0 + wn + ni * 16 + l15;
        const int h = col >> 6, dk = col & 63;
        const float bb = bias[col];
#pragma unroll
        for (int mi = 0; mi < 4; ++mi) {
            const int rowb = row0 + wm + mi * 16 + g * 4;
            const int b = rowb >> 11;
            const int l = rowb & (L_ - 1);
            const int bh = b * 16 + h;
            if (z == 2) {
                bf16x4 o;
#pragma unroll
                for (int r = 0; r < 4; ++r) o[r] = f2bf(acc[mi][ni][r] + bb);
                *(bf16x4*)&vT[(size_t)(bh * 64 + dk) * L_ + l] = o;
            } else {
                short* dst = (z == 0) ? qh : kh;
                const float sc = (z == 0) ? QSCALE : 1.0f;
#pragma unroll
                for (int r = 0; r < 4; ++r)
                    dst[((size_t)bh * L_ + l + r) * DK_ + dk] = f2bf((acc[mi][ni][r] + bb) * sc);
            }
        }
    }
}

// ------------------------------------------------------------ fused attention v11
// Round-8 schedule verbatim; softmax with FIXED reference c=0 (shift-invariance):
// pass 1 = pure sum of exp2 (no max tracking), pass 2: p = exp2(sa + li), li=-log2(s).
__global__ __launch_bounds__(512, 8)
void attn_mfma(const short* __restrict__ qh, const short* __restrict__ kh,
               const short* __restrict__ vT,
               float* __restrict__ attn, short* __restrict__ ctxTb)
{
    const int bid = blockIdx.x;
    const int wg = (bid & 7) * 128 + (bid >> 3);      // XCD-contiguous
    const int bh = wg >> 5;
    const int q0 = (wg & 31) * 64;

    const int tid = threadIdx.x;
    const int lane = tid & 63;
    const int w = tid >> 6;
    const int wq = w >> 1, wk = w & 1;
    const int l15 = lane & 15, g = lane >> 4;

    __shared__ short SM[17408];
    short* const Kb0 = SM;
    short* const Kb1 = SM + 4096;
    short* const Vb  = SM + 8192;
    short* const Psb = SM + 12288;                    // 64 x 72
    float* const stat = (float*)(SM + 16896);         // [4][2][16] row-sums

    const short* kbase = kh + (size_t)bh * (L_ * DK_);
    const short* vbase = vT + (size_t)bh * (DK_ * L_);

    const int lr = lane >> 3, ls = lane & 7;
    const int srow = w * 8 + lr;
    const short* kSrc = kbase + (size_t)srow * DK_ + ((ls ^ (srow & 7)) * 8);
    const short* vSrc = vbase + (size_t)srow * L_ + ((ls ^ (srow & 7)) * 8);

    bf16x8 qf[2];
#pragma unroll
    for (int ks = 0; ks < 2; ++ks)
        qf[ks] = *(const bf16x8*)&qh[((size_t)bh * L_ + q0 + wq * 16 + l15) * DK_ + ks * 32 + g * 8];

    int kbOff[2][2], vbOff[4];
#pragma unroll
    for (int cc = 0; cc < 2; ++cc)
#pragma unroll
        for (int ks = 0; ks < 2; ++ks) {
            const int row = wk * 32 + cc * 16 + l15;
            kbOff[cc][ks] = row * 64 + (((ks * 4 + g) ^ (row & 7)) * 8);
        }
#pragma unroll
    for (int nf = 0; nf < 4; ++nf) {
        const int row = nf * 16 + l15;
        vbOff[nf] = row * 64 + (((wk * 4 + g) ^ (row & 7)) * 8);
    }

    // ---------------- pass 1: SUM-ONLY stats (c=0), 4-deep K pipeline
    float s[4];
#pragma unroll
    for (int r = 0; r < 4; ++r) s[r] = 0.f;

#pragma unroll
    for (int i = 0; i < 3; ++i)
        gload16(kSrc + (size_t)i * 64 * DK_, SM + (i << 12) + w * 512);
    asm volatile("s_waitcnt vmcnt(2)" ::: "memory");   // K(0) landed
    __builtin_amdgcn_sched_barrier(0);
    __builtin_amdgcn_s_barrier();

    for (int t = 0; t < 32; ++t) {
        if (t < 29)
            gload16(kSrc + (size_t)(t + 3) * 64 * DK_, SM + (((t + 3) & 3) << 12) + w * 512);
        const short* kb = SM + ((t & 3) << 12);
        f32x4 sa[2];
#pragma unroll
        for (int cc = 0; cc < 2; ++cc) sa[cc] = (f32x4)0.f;
        __builtin_amdgcn_s_setprio(1);
#pragma unroll
        for (int cc = 0; cc < 2; ++cc)
#pragma unroll
            for (int ks = 0; ks < 2; ++ks)
                sa[cc] = __builtin_amdgcn_mfma_f32_16x16x32_bf16(qf[ks], *(const bf16x8*)&kb[kbOff[cc][ks]], sa[cc], 0, 0, 0);
        __builtin_amdgcn_s_setprio(0);
#pragma unroll
        for (int r = 0; r < 4; ++r)
            s[r] += exp2f(sa[0][r]) + exp2f(sa[1][r]);
        if (t < 29)       { asm volatile("s_waitcnt vmcnt(2)" ::: "memory"); }
        else if (t == 29) { asm volatile("s_waitcnt vmcnt(1)" ::: "memory"); }
        else if (t == 30) { asm volatile("s_waitcnt vmcnt(0)" ::: "memory"); }
        __builtin_amdgcn_sched_barrier(0);
        if (t < 31) __builtin_amdgcn_s_barrier();
    }
    // cross-lane sum over the 16-lane col groups
#pragma unroll
    for (int mask = 1; mask <= 8; mask <<= 1)
#pragma unroll
        for (int r = 0; r < 4; ++r)
            s[r] += __shfl_xor(s[r], mask);
    if (l15 == 0) {
#pragma unroll
        for (int r = 0; r < 4; ++r)
            stat[(wq * 2 + wk) * 16 + g * 4 + r] = s[r];
    }
    gload16(kSrc, SM + w * 512);                       // K(0) for pass 2 -> Kb0
    asm volatile("s_waitcnt lgkmcnt(0)" ::: "memory"); // stat visible
    __builtin_amdgcn_s_barrier();
    float li[4];                                       // -log2(row sum)
#pragma unroll
    for (int r = 0; r < 4; ++r) {
        const float st = stat[(wq * 2 + 0) * 16 + g * 4 + r]
                       + stat[(wq * 2 + 1) * 16 + g * 4 + r];
        li[r] = -log2f(st);
    }

    f32x4 cacc[4];
#pragma unroll
    for (int nf = 0; nf < 4; ++nf) cacc[nf] = (f32x4)0.f;

    float* attnB = attn + ((size_t)bh * L_ + q0) * L_;

    asm volatile("s_waitcnt vmcnt(0)" ::: "memory");   // K(0) landed
    __builtin_amdgcn_sched_barrier(0);
    __builtin_amdgcn_s_barrier();

    // ---------------- pass 2: recompute, fp32 register attn stores, PV
    // per-iter vmem issue order: V(t), K(t+1), stores(t)x8
    for (int t = 0; t < 32; ++t) {
        if (t) {
            asm volatile("s_waitcnt vmcnt(8)" ::: "memory");   // K(t) landed; stores keep flying
            __builtin_amdgcn_sched_barrier(0);
            __builtin_amdgcn_s_barrier();
        }
        gload16(vSrc + t * 64, Vb + w * 512);                   // V(t)
        {
            const int tn = (t < 31) ? t + 1 : t;                // uniform issue count
            gload16(kSrc + (size_t)tn * 64 * DK_, ((t & 1) ? Kb0 : Kb1) + w * 512);
        }
        const short* kb = (t & 1) ? Kb1 : Kb0;
        f32x4 sa[2];
#pragma unroll
        for (int cc = 0; cc < 2; ++cc) sa[cc] = (f32x4)0.f;
        __builtin_amdgcn_s_setprio(1);
#pragma unroll
        for (int cc = 0; cc < 2; ++cc)
#pragma unroll
            for (int ks = 0; ks < 2; ++ks)
                sa[cc] = __builtin_amdgcn_mfma_f32_16x16x32_bf16(qf[ks], *(const bf16x8*)&kb[kbOff[cc][ks]], sa[cc], 0, 0, 0);
        __builtin_amdgcn_s_setprio(0);
#pragma unroll
        for (int cc = 0; cc < 2; ++cc)
#pragma unroll
            for (int r = 0; r < 4; ++r) {
                const float p = exp2f(sa[cc][r] + li[r]);       // normalized (c=0 softmax)
                Psb[(wq * 16 + g * 4 + r) * 72 + wk * 32 + cc * 16 + l15] = f2bf(p);
                __builtin_nontemporal_store(
                    p, attnB + (size_t)(wq * 16 + g * 4 + r) * L_ + t * 64 + wk * 32 + cc * 16 + l15);
            }
        // V(t) landed (9 newer: K(t+1)+8 stores), Psb visible
        asm volatile("s_waitcnt vmcnt(9) lgkmcnt(0)" ::: "memory");
        __builtin_amdgcn_sched_barrier(0);
        __builtin_amdgcn_s_barrier();
        const bf16x8 pa = *(const bf16x8*)&Psb[(wq * 16 + l15) * 72 + wk * 32 + g * 8];
        __builtin_amdgcn_s_setprio(1);
#pragma unroll
        for (int nf = 0; nf < 4; ++nf)
            cacc[nf] = __builtin_amdgcn_mfma_f32_16x16x32_bf16(pa, *(const bf16x8*)&Vb[vbOff[nf]], cacc[nf], 0, 0, 0);
        __builtin_amdgcn_s_setprio(0);
    }

    // epilogue: combine kv-halves, store ctx^T bf16
    __syncthreads();
    float* scr = (float*)Kb0;
    float* scr1 = (float*)Kb1;
    if (wk) {
#pragma unroll
        for (int nf = 0; nf < 4; ++nf) {
            float* p = (nf < 2) ? scr : scr1;
            *(f32x4*)&p[(((wq * 2) + (nf & 1)) * 64 + lane) * 4] = cacc[nf];
        }
    }
    __syncthreads();
    if (!wk) {
#pragma unroll
        for (int nf = 0; nf < 4; ++nf) {
            const float* p = (nf < 2) ? scr : scr1;
            const f32x4 o = cacc[nf] + *(const f32x4*)&p[(((wq * 2) + (nf & 1)) * 64 + lane) * 4];
            bf16x4 ob;
#pragma unroll
            for (int r = 0; r < 4; ++r) ob[r] = f2bf(o[r]);
            *(bf16x4*)&ctxTb[(size_t)(bh * 64 + nf * 16 + l15) * L_ + q0 + wq * 16 + g * 4] = ob;
        }
    }
}

// ------------------------------------------------------------ output projection (round-8: MFMA, BM=128 BN=64)
__global__ __launch_bounds__(256)
void out_mfma(const short* __restrict__ ctxTb, const short* __restrict__ xoutb,
              const short* __restrict__ WoT, const float* __restrict__ bo,
              float* __restrict__ out)
{
    const int flat = blockIdx.y * 16 + blockIdx.x;
    const int wgs = (flat & 7) * 64 + (flat >> 3);
    const int col0 = (wgs & 15) * 64;
    const int row0 = (wgs >> 4) * 128;
    const int tid = threadIdx.x;
    const int lane = tid & 63;
    const int w = tid >> 6;
    const int wm = (w >> 1) * 64, wn = (w & 1) * 32;
    const int l15 = lane & 15, g = lane >> 4;
    const int sub = lane >> 3, slt = lane & 7;

    __shared__ short As[128 * 64];
    __shared__ short Bs[64 * 64];

    const short* pA1[4]; const short* pA2[4]; const short* pB[2];
    short* ldsA[4]; short* ldsB[2];
#pragma unroll
    for (int i = 0; i < 4; ++i) {
        const int r = w * 32 + i * 8 + sub;
        const int rr = row0 + r;
        const int b = rr >> 11, l_ = rr & (L_ - 1);
        const int bh = b * 16 + (l_ >> 7), d = (l_ & 127) >> 1;
        const size_t off1 = ((size_t)(bh * 64 + d) << 11) + (size_t)((l_ & 1) << 10);
        const int sc = ((slt ^ (r & 7)) * 8);
        pA1[i] = ctxTb + off1 + sc;
        pA2[i] = xoutb + (size_t)rr * DIM_ + sc;
        ldsA[i] = &As[(w * 32 + i * 8) * 64];
    }
#pragma unroll
    for (int i = 0; i < 2; ++i) {
        const int r = w * 16 + i * 8 + sub;
        const int sc = ((slt ^ (r & 7)) * 8);
        pB[i]  = WoT + (size_t)(col0 + r) * (2 * DIM_) + sc;
        ldsB[i] = &Bs[(w * 16 + i * 8) * 64];
    }

    f32x4 acc[4][2];
#pragma unroll
    for (int mi = 0; mi < 4; ++mi)
#pragma unroll
        for (int ni = 0; ni < 2; ++ni) acc[mi][ni] = (f32x4)0.f;

    for (int k0 = 0; k0 < 2 * DIM_; k0 += 64) {
        const bool first = (k0 < DIM_);
        const int kk = first ? k0 : k0 - DIM_;
#pragma unroll
        for (int i = 0; i < 4; ++i)
            gload16(first ? (pA1[i] + kk) : (pA2[i] + kk), ldsA[i]);
#pragma unroll
        for (int i = 0; i < 2; ++i)
            gload16(pB[i] + k0, ldsB[i]);
        __syncthreads();
        bf16x8 af[4][2], bfr[2][2];
#pragma unroll
        for (int mi = 0; mi < 4; ++mi) {
            const int wa = wm + mi * 16 + l15;
#pragma unroll
            for (int ks = 0; ks < 2; ++ks)
                af[mi][ks] = *(const bf16x8*)&As[wa * 64 + (((ks * 4 + g) ^ (wa & 7)) * 8)];
        }
#pragma unroll
        for (int ni = 0; ni < 2; ++ni) {
            const int wb = wn + ni * 16 + l15;
#pragma unroll
            for (int ks = 0; ks < 2; ++ks)
                bfr[ni][ks] = *(const bf16x8*)&Bs[wb * 64 + (((ks * 4 + g) ^ (wb & 7)) * 8)];
        }
        __builtin_amdgcn_s_setprio(1);
#pragma unroll
        for (int mi = 0; mi < 4; ++mi)
#pragma unroll
            for (int ni = 0; ni < 2; ++ni)
#pragma unroll
                for (int ks = 0; ks < 2; ++ks)
                    acc[mi][ni] = __builtin_amdgcn_mfma_f32_16x16x32_bf16(af[mi][ks], bfr[ni][ks], acc[mi][ni], 0, 0, 0);
        __builtin_amdgcn_s_setprio(0);
        __syncthreads();
    }

#pragma unroll
    for (int ni = 0; ni < 2; ++ni) {
        const int col = col0 + wn + ni * 16 + l15;
        const float bb = bo[col];
#pragma unroll
        for (int mi = 0; mi < 4; ++mi) {
            const int rowb = row0 + wm + mi * 16 + g * 4;
#pragma unroll
            for (int r = 0; r < 4; ++r)
                out[(size_t)(rowb + r) * DIM_ + col] = tanhf(acc[mi][ni][r] + bb);
        }
    }
}

// ------------------------------------------------------------ launch
extern "C" void kernel_launch(void* const* d_in, const int* in_sizes, int n_in,
                              void* d_out, int out_size, void* d_ws, size_t ws_size,
                              hipStream_t stream)
{
    const float* xout = (const float*)d_in[0];
    const float* xctx = (const float*)d_in[1];
    const float* Wq = (const float*)d_in[2];
    const float* bq = (const float*)d_in[3];
    const float* Wk = (const float*)d_in[4];
    const float* bk = (const float*)d_in[5];
    const float* Wv = (const float*)d_in[6];
    const float* bv = (const float*)d_in[7];
    const float* Wo = (const float*)d_in[8];
    const float* bo = (const float*)d_in[9];

    float* out  = (float*)d_out;
    float* attn = out + (size_t)M_ * DIM_;

    short* ws = (short*)d_ws;
    short* xoutb = ws;
    short* xctxb = xoutb + (size_t)M_ * DIM_;
    short* WqT   = xctxb + (size_t)M_ * DIM_;
    short* WkT   = WqT + (size_t)DIM_ * DIM_;
    short* WvT   = WkT + (size_t)DIM_ * DIM_;
    short* WoT   = WvT + (size_t)DIM_ * DIM_;
    short* qh    = WoT + (size_t)2 * DIM_ * DIM_;
    short* kh    = qh + (size_t)BH_ * L_ * DK_;
    short* vT    = kh + (size_t)BH_ * L_ * DK_;
    short* ctxTb = vT + (size_t)BH_ * L_ * DK_;

    prep<<<6144, 256, 0, stream>>>(xout, xctx, Wq, Wk, Wv, Wo,
                                   xoutb, xctxb, WqT, WkT, WvT, WoT);
    qkv_mfma<<<dim3(8, 32, 3), 256, 0, stream>>>(
        xoutb, xctxb, WqT, WkT, WvT, bq, bk, bv, qh, kh, vT);
    attn_mfma<<<1024, 512, 0, stream>>>(qh, kh, vT, attn, ctxTb);
    out_mfma<<<dim3(16, 32), 256, 0, stream>>>(ctxTb, xoutb, WoT, bo, out);
}